// Round 15
// baseline (1187.076 us; speedup 1.0000x reference)
//
#include <hip/hip_runtime.h>
#include <hip/hip_bf16.h>

typedef _Float16 f16;
typedef _Float16 f16x2 __attribute__((ext_vector_type(2)));
typedef _Float16 f16x4 __attribute__((ext_vector_type(4)));
typedef _Float16 f16x8 __attribute__((ext_vector_type(8)));
typedef float f32x4 __attribute__((ext_vector_type(4)));

#define S_LEN 4096
#define DIM   512
#define NH    8
#define DH    64
#define BATCH 2
#define BHDIM (BATCH*NH)   // 16
#define ROWS2 (BHDIM*S_LEN) // 65536

// Q pre-scale: 1/sqrt(64) * log2(e)  (softmax done in exp2 domain)
#define QSCALE 0.18033688011112042f

__device__ __forceinline__ void gld16(const f16* g, f16* l) {
#if __has_builtin(__builtin_amdgcn_global_load_lds)
  __builtin_amdgcn_global_load_lds((const __attribute__((address_space(1))) void*)g,
                                   (__attribute__((address_space(3))) void*)l, 16, 0, 0);
#else
  *(f16x8*)l = *(const f16x8*)g;
#endif
}

__device__ __forceinline__ float fexp2(float x) {
#if __has_builtin(__builtin_amdgcn_exp2f)
  return __builtin_amdgcn_exp2f(x);
#else
  return exp2f(x);
#endif
}

__device__ __forceinline__ f16x2 pk2(float a, float b) {
#if __has_builtin(__builtin_amdgcn_cvt_pkrtz)
  auto r = __builtin_amdgcn_cvt_pkrtz(a, b);   // __fp16 ext_vector(2); same bits
  f16x2 o; __builtin_memcpy(&o, &r, sizeof(o));
  return o;
#else
  f16x2 r; r[0] = (f16)a; r[1] = (f16)b; return r;
#endif
}

// ---------------- Fused prep: rmsnorm + weight transpose + rope tables ----------------
// blocks [0,8192): RMSNorm row; [8192,9216): transpose 32x32 tile; [9216,9728): rope.
__global__ __launch_bounds__(256) void prep_kernel(
    const float* __restrict__ x, const float* __restrict__ scale,
    const float* __restrict__ Wq, const float* __restrict__ Wk,
    const float* __restrict__ Wv, const float* __restrict__ Wo,
    f16* __restrict__ xn, f16* __restrict__ wt_qkv, f16* __restrict__ wo_t,
    float* __restrict__ ctab, float* __restrict__ stab) {
  int bid = blockIdx.x;
  int tid = threadIdx.x;
  if (bid < 8192) {                      // ---- RMSNorm ----
    const float* xr = x + (size_t)bid * DIM;
    float2 v = *(const float2*)(xr + tid*2);
    float ss = v.x*v.x + v.y*v.y;
    #pragma unroll
    for (int off = 32; off > 0; off >>= 1) ss += __shfl_down(ss, off);
    __shared__ float red[4];
    if ((tid & 63) == 0) red[tid >> 6] = ss;
    __syncthreads();
    float tot = red[0] + red[1] + red[2] + red[3];
    float inv = rsqrtf(tot * (1.0f/DIM) + 1e-6f);
    float2 s = *(const float2*)(scale + tid*2);
    xn[(size_t)bid*DIM + tid*2+0] = (f16)(v.x*inv*s.x);
    xn[(size_t)bid*DIM + tid*2+1] = (f16)(v.y*inv*s.y);
  } else if (bid < 9216) {               // ---- weight transpose (f32 -> f16^T) ----
    __shared__ f16 tile[32][33];
    int b2 = bid - 8192;
    int mat = b2 >> 8;                   // 256 blocks per matrix
    int rem = b2 & 255;
    int k0 = (rem >> 4) * 32, n0 = (rem & 15) * 32;
    const float* src = (mat == 0) ? Wq : (mat == 1) ? Wk : (mat == 2) ? Wv : Wo;
    f16* dst = (mat < 3) ? (wt_qkv + (size_t)mat*DIM*DIM) : wo_t;
    int tx = tid & 31, ty = tid >> 5;    // (32, 8)
    #pragma unroll
    for (int i = 0; i < 32; i += 8)
      tile[ty+i][tx] = (f16)src[(size_t)(k0+ty+i)*DIM + n0+tx];
    __syncthreads();
    #pragma unroll
    for (int i = 0; i < 32; i += 8)
      dst[(size_t)(n0+ty+i)*DIM + k0+tx] = tile[tx][ty+i];
  } else {                               // ---- rope cos/sin tables ----
    int idx = (bid - 9216)*256 + tid;    // 0..131071
    int t = idx >> 5, d = idx & 31;
    float theta = exp2f(-(float)d * (19.931568569324174f / 32.0f));
    float sv, cv;
    sincosf((float)t * theta, &sv, &cv);
    ctab[idx] = cv; stab[idx] = sv;
  }
}

// ------------- m97-style 128x128 GEMM core: C = A[M,512] * Bt[N,512]^T -------------
__device__ __forceinline__ void gemm128_acc(
    const f16* __restrict__ A, const f16* __restrict__ Bt,
    int m0, int n0, f16* As, f16* Bs, f32x4 (&acc)[4][4]) {
  const int tid = threadIdx.x;
  const int wave = tid >> 6, lane = tid & 63;
  const int l16 = lane & 15, quad = lane >> 4;
  const int mrow = (wave & 1) * 64, ncol = (wave >> 1) * 64;
  const int srow = tid >> 3;                    // 0..31
  const int gc = (tid & 7) ^ ((tid >> 3) & 7);  // swizzled source chunk

  for (int k0 = 0; k0 < DIM; k0 += 64) {
    if (k0) __syncthreads();
    #pragma unroll
    for (int i = 0; i < 4; i++) {
      gld16(A  + (size_t)(m0 + i*32 + srow)*DIM + k0 + gc*8, As + i*2048 + tid*8);
      gld16(Bt + (size_t)(n0 + i*32 + srow)*DIM + k0 + gc*8, Bs + i*2048 + tid*8);
    }
    __syncthreads();
    #pragma unroll
    for (int kc = 0; kc < 2; kc++) {
      f16x8 a[4], b[4];
      #pragma unroll
      for (int mt = 0; mt < 4; mt++) {
        int row = mrow + mt*16 + l16;
        a[mt] = *(const f16x8*)(As + row*64 + (((quad + 4*kc) ^ (l16 & 7)) * 8));
      }
      #pragma unroll
      for (int nt = 0; nt < 4; nt++) {
        int row = ncol + nt*16 + l16;
        b[nt] = *(const f16x8*)(Bs + row*64 + (((quad + 4*kc) ^ (l16 & 7)) * 8));
      }
      #pragma unroll
      for (int mt = 0; mt < 4; mt++)
        #pragma unroll
        for (int nt = 0; nt < 4; nt++)
          acc[mt][nt] = __builtin_amdgcn_mfma_f32_16x16x32_f16(a[mt], b[nt], acc[mt][nt], 0, 0, 0);
    }
  }
}

// ------------- QKV GEMM + table-RoPE + Q prescale -------------
// V output layout: within each 64-token group, token at permuted position
// pos = ((mt>>1)*4 + quad)*8 + (mt&1)*4 + r  so the attn PV fragment for
// (chunk c, quad) is ONE contiguous f16x8 matching the in-register P order
// sigma(c,quad,j) = (2c + (j>>2))*16 + quad*4 + (j&3).  [verified r9-r14]
__global__ __launch_bounds__(256) void qkv_gemm_kernel(
    const f16* __restrict__ xn, const f16* __restrict__ wt,
    const float* __restrict__ ctab, const float* __restrict__ stab,
    f16* __restrict__ qbuf, f16* __restrict__ kbuf, f16* __restrict__ vt) {
  __shared__ __align__(16) f16 As[128*64], Bs[128*64];
  int m0 = blockIdx.x * 128, n0 = blockIdx.y * 128;
  f32x4 acc[4][4] = {};
  gemm128_acc(xn, wt, m0, n0, As, Bs, acc);

  const int tid = threadIdx.x;
  const int wave = tid >> 6, lane = tid & 63;
  const int l16 = lane & 15, quad = lane >> 4;
  int ncol = n0 + (wave >> 1) * 64;      // head-aligned
  int which = ncol >> 9;                 // 0=q 1=k 2=v (wave-uniform)
  int head = (ncol >> 6) & 7;
  int mbase = m0 + (wave & 1) * 64;

  if (which <= 1) {                      // fused RoPE from tables
    #pragma unroll
    for (int mt = 0; mt < 4; mt++)
      #pragma unroll
      for (int nt = 0; nt < 2; nt++) {
        int d = nt*16 + l16;
        #pragma unroll
        for (int r = 0; r < 4; r++) {
          int t = (mbase + mt*16 + quad*4 + r) & 4095;
          float cv = ctab[t*32 + d], sv = stab[t*32 + d];
          float x1 = acc[mt][nt][r], x2 = acc[mt][nt+2][r];
          acc[mt][nt][r]   = x1*cv - x2*sv;
          acc[mt][nt+2][r] = x1*sv + x2*cv;
        }
      }
  }
  if (which < 2) {
    float osc = (which == 0) ? QSCALE : 1.0f;
    f16* dst = which ? kbuf : qbuf;
    #pragma unroll
    for (int mt = 0; mt < 4; mt++)
      #pragma unroll
      for (int nt = 0; nt < 4; nt++)
        #pragma unroll
        for (int r = 0; r < 4; r++) {
          int m = mbase + mt*16 + quad*4 + r;
          int b = m >> 12, t = m & 4095;
          dst[(((size_t)(b*NH + head))*S_LEN + t)*DH + nt*16 + l16] = (f16)(acc[mt][nt][r]*osc);
        }
  } else {                               // V transposed + pi-permuted token order
    #pragma unroll
    for (int mt = 0; mt < 4; mt++)
      #pragma unroll
      for (int nt = 0; nt < 4; nt++) {
        int m = mbase + mt*16 + quad*4;
        int b = m >> 12, tcol = m & 4095;
        int grp = tcol & ~63;
        int pos = ((mt >> 1)*4 + quad)*8 + (mt & 1)*4;
        int d = nt*16 + l16;
        f16x4 v4 = {(f16)acc[mt][nt][0], (f16)acc[mt][nt][1],
                    (f16)acc[mt][nt][2], (f16)acc[mt][nt][3]};
        *(f16x4*)(vt + ((size_t)((b*NH + head)*DH + d))*S_LEN + grp + pos) = v4;
      }
  }
}

// ------------- Flash attention (causal), 4-band 8-wave blocks + split-K parity -------------
// 1024 blocks x 512 threads. Block = (p2, hf, bh) covering FOUR bands
// {127-p2, 64+p2, 63-p2, p2} whose tile counts sum to a constant 130 for every
// p2 (exact compute balance). Wave w: band bi = w>>1, 16-row half w&1.
// Each staged 64-key tile feeds 4 bands (staging iterations per CU halve vs
// r13's 2-band blocks); 4 blocks/CU x 8 waves = 32 waves/CU dispatched.
// Per-wave body identical to r13 (44 VGPR <= 64 cap of (512,8)).
__global__ __launch_bounds__(512, 8) void attn_kernel(
    const f16* __restrict__ qbuf, const f16* __restrict__ kbuf,
    const f16* __restrict__ vtb, f16* __restrict__ po,
    float* __restrict__ pm, float* __restrict__ pl) {
  int bid = blockIdx.x;                  // 0..1023
  int bh  = bid & 15;
  int hf  = (bid >> 4) & 1;              // KV-tile parity half
  int p2  = bid >> 5;                    // 0..31

  int tid = threadIdx.x;
  int wave = tid >> 6, lane = tid & 63;
  int l16 = lane & 15, quad = lane >> 4;
  int bi = wave >> 1, half = wave & 1;

  const f16* Q = qbuf + (size_t)bh*S_LEN*DH;
  const f16* K = kbuf + (size_t)bh*S_LEN*DH;
  const f16* V = vtb  + (size_t)bh*DH*S_LEN;   // [dh][s], pi-permuted in s

  // 4 bands partition [0,128): {127-p2 | 96..127, 64+p2 | 64..95, 63-p2 | 32..63, p2 | 0..31}
  int bv = (bi == 0) ? (127 - p2) : (bi == 1) ? (64 + p2)
         : (bi == 2) ? (63 - p2)  : p2;
  int tc = (bv >> 1) + 1;                // this band's KV-tile count
  int T0 = ((127 - p2) >> 1) + 1;        // block loop basis (heaviest band)
  int nloc = (T0 - hf + 1) >> 1;         // this parity's loop count
  int rbase = bv*32 + half*16;           // wave's 16 q-rows

  // Q fragments (B-operand of S^T = K Q^T)
  f16x8 qa0, qa1;
  {
    const f16* qrow = Q + (size_t)(rbase + l16)*DH + quad*8;
    qa0 = *(const f16x8*)(qrow);
    qa1 = *(const f16x8*)(qrow + 32);
  }

  f32x4 o[4] = {};                       // O C-layout [qrow=quad*4+r][dh=dnt*16+l16]
  float m_i = -1e30f;
  float l_i = 0.f;                       // per-lane partial (this quad); reduced in epilogue

  // K [2 bufs][64 kv][64 dh], V [2 bufs][64 dh][64 kv(perm)]  (32 KB)
  __shared__ __align__(16) f16 kt[2*4096];
  __shared__ __align__(16) f16 vs[2*4096];

  const int srow = tid >> 3;                     // 0..63
  const int gcs = (tid & 7) ^ (srow & 7);        // swizzled source chunk

  #define STAGE(buf, kv)                                                        \
    do {                                                                        \
      f16* ktb = kt + (buf)*4096;                                               \
      f16* vsb = vs + (buf)*4096;                                               \
      gld16(K + (size_t)((kv) + srow)*DH + gcs*8, ktb + tid*8);                 \
      gld16(V + (size_t)srow*S_LEN + (kv) + gcs*8, vsb + tid*8);                \
    } while (0)

  STAGE(0, hf*64);
  __syncthreads();                       // drains vmcnt -> first tile staged

  for (int itl = 0; itl < nloc; ++itl) {
    int g = 2*itl + hf;
    int kv0 = g * 64;
    int cur = itl & 1;
    if (itl + 1 < nloc) STAGE(cur ^ 1, kv0 + 128);   // async prefetch next parity tile

    const f16* ktc = kt + cur*4096;
    const f16* vsc = vs + cur*4096;

    if (g < tc) {                        // wave-uniform: this band still active
      bool diag = (g == tc - 1);
      int ntl = diag ? ((bv & 1) ? 4 : 2) : 4;    // live 16-key frags
      int kcl = ntl >> 1;                         // live 32-key chunks

      // ---- S^T = K Q^T ----
      f32x4 st[4];
      #pragma unroll
      for (int nt = 0; nt < 4; nt++) {
        if (nt >= ntl) continue;
        int row = nt*16 + l16;
        f16x8 kf0 = *(const f16x8*)(ktc + row*64 + (((quad)     ^ (row & 7))*8));
        f16x8 kf1 = *(const f16x8*)(ktc + row*64 + (((quad + 4) ^ (row & 7))*8));
        f32x4 z = {};
        z = __builtin_amdgcn_mfma_f32_16x16x32_f16(kf0, qa0, z, 0, 0, 0);
        st[nt] = __builtin_amdgcn_mfma_f32_16x16x32_f16(kf1, qa1, z, 0, 0, 0);
      }

      // ---- softmax (per q-row l16, replicated over quads) ----
      int qglob = rbase + l16;
      float rmx = -1e30f;
      #pragma unroll
      for (int nt = 0; nt < 4; nt++) {
        if (nt >= ntl) continue;
        if (diag) {
          int kb = kv0 + nt*16 + quad*4;
          #pragma unroll
          for (int r = 0; r < 4; r++) {
            float v = st[nt][r];
            if (kb + r > qglob) v = -1e30f;
            st[nt][r] = v;
            rmx = fmaxf(rmx, v);
          }
        } else {
          #pragma unroll
          for (int r = 0; r < 4; r++) rmx = fmaxf(rmx, st[nt][r]);
        }
      }
      rmx = fmaxf(rmx, __shfl_xor(rmx, 16));
      rmx = fmaxf(rmx, __shfl_xor(rmx, 32));
      // defer-max (T13): skip O-rescale while running max grows < THR=8
      if (!__all(rmx <= m_i + 8.0f)) {
        float mnew = fmaxf(m_i, rmx);
        float alpha = fexp2(m_i - mnew);
        m_i = mnew;
        float al[4];
        #pragma unroll
        for (int r = 0; r < 4; r++) al[r] = __shfl(alpha, quad*4 + r);
        #pragma unroll
        for (int dnt = 0; dnt < 4; dnt++)
          #pragma unroll
          for (int r = 0; r < 4; r++) o[dnt][r] *= al[r];
        l_i *= alpha;
      }
      float mref = m_i;
      float rs = 0.f;
      f16x8 pa[2];
      #pragma unroll
      for (int c = 0; c < 2; c++) {
        if (c >= kcl) continue;
        float e0 = fexp2(st[2*c  ][0] - mref);
        float e1 = fexp2(st[2*c  ][1] - mref);
        float e2 = fexp2(st[2*c  ][2] - mref);
        float e3 = fexp2(st[2*c  ][3] - mref);
        float e4 = fexp2(st[2*c+1][0] - mref);
        float e5 = fexp2(st[2*c+1][1] - mref);
        float e6 = fexp2(st[2*c+1][2] - mref);
        float e7 = fexp2(st[2*c+1][3] - mref);
        rs += ((e0+e1)+(e2+e3)) + ((e4+e5)+(e6+e7));
        f16x4 h0 = __builtin_shufflevector(pk2(e0,e1), pk2(e2,e3), 0,1,2,3);
        f16x4 h1 = __builtin_shufflevector(pk2(e4,e5), pk2(e6,e7), 0,1,2,3);
        pa[c] = __builtin_shufflevector(h0, h1, 0,1,2,3,4,5,6,7);
      }
      l_i += rs;

      // ---- PV: one b128 V read per fragment (perm layout) ----
      #pragma unroll
      for (int c = 0; c < 2; c++) {
        if (c >= kcl) continue;
        #pragma unroll
        for (int dnt = 0; dnt < 4; dnt++) {
          int vr = dnt*16 + l16;
          f16x8 vf = *(const f16x8*)(vsc + vr*64 + (((c*4 + quad) ^ (vr & 7))*8));
          o[dnt] = __builtin_amdgcn_mfma_f32_16x16x32_f16(pa[c], vf, o[dnt], 0, 0, 0);
        }
      }
    }

    __syncthreads();  // all waves done reading cur; staged loads (vmcnt) drained
  }
  #undef STAGE

  // epilogue: write normalized partials + (m, l) per row
  {
    float lf = l_i;
    lf += __shfl_xor(lf, 16);
    lf += __shfl_xor(lf, 32);            // row-consistent l (indexed by l16)
    if (quad == 0) {                      // one lane per row writes m, l
      int t = rbase + l16;
      pm[(size_t)(hf*BHDIM + bh)*S_LEN + t] = m_i;
      pl[(size_t)(hf*BHDIM + bh)*S_LEN + t] = lf;
    }
    float lr[4];
    #pragma unroll
    for (int r = 0; r < 4; r++) lr[r] = __shfl(lf, quad*4 + r);
    #pragma unroll
    for (int r = 0; r < 4; r++) {
      float invl = (lr[r] > 0.f) ? 1.0f / lr[r] : 0.f;
      int t = rbase + quad*4 + r;
      size_t rowoff = ((size_t)(hf*BHDIM + bh)*S_LEN + t)*DH;
      #pragma unroll
      for (int dnt = 0; dnt < 4; dnt++)
        po[rowoff + dnt*16 + l16] = (f16)(o[dnt][r]*invl);
    }
  }
}

// ------------- Merge split-K halves: ao = w0*po0 + w1*po1 -------------
__global__ __launch_bounds__(256) void merge_kernel(
    const f16* __restrict__ po, const float* __restrict__ pm,
    const float* __restrict__ pl, f16* __restrict__ ao) {
  int idx = blockIdx.x*256 + threadIdx.x;     // 0..262143
  int r_ = idx >> 2, q = idx & 3;             // row, 16-dim quarter
  int bh = r_ >> 12, t = r_ & 4095;
  float m0 = pm[r_], m1 = pm[ROWS2 + r_];
  float l0 = pl[r_], l1 = pl[ROWS2 + r_];
  float M  = fmaxf(m0, m1);
  float a0 = l0 * fexp2(m0 - M);
  float a1 = l1 * fexp2(m1 - M);
  float inv = 1.0f / (a0 + a1);
  float w0 = a0 * inv, w1 = a1 * inv;
  const f16* p0 = po + (size_t)r_*DH + q*16;
  const f16* p1 = po + (size_t)(ROWS2 + r_)*DH + q*16;
  int b = bh >> 3, h = bh & 7;
  f16* dst = ao + ((size_t)(b*S_LEN + t))*DIM + h*DH + q*16;
  f16x8 v0a = *(const f16x8*)(p0), v0b = *(const f16x8*)(p0 + 8);
  f16x8 v1a = *(const f16x8*)(p1), v1b = *(const f16x8*)(p1 + 8);
  f16x8 oa, ob;
  #pragma unroll
  for (int j = 0; j < 8; j++) {
    oa[j] = (f16)(w0*(float)v0a[j] + w1*(float)v1a[j]);
    ob[j] = (f16)(w0*(float)v0b[j] + w1*(float)v1b[j]);
  }
  *(f16x8*)dst = oa;
  *(f16x8*)(dst + 8) = ob;
}

// ------------- Output GEMM: ao[8192,512] @ Wo -> out f32 -------------
__global__ __launch_bounds__(256) void out_gemm_kernel(
    const f16* __restrict__ ao, const f16* __restrict__ wot,
    float* __restrict__ out) {
  __shared__ __align__(16) f16 As[128*64], Bs[128*64];
  int m0 = blockIdx.x * 128, n0 = blockIdx.y * 128;
  f32x4 acc[4][4] = {};
  gemm128_acc(ao, wot, m0, n0, As, Bs, acc);

  const int tid = threadIdx.x;
  const int wave = tid >> 6, lane = tid & 63;
  const int l16 = lane & 15, quad = lane >> 4;
  int ncol = n0 + (wave >> 1) * 64;
  int mbase = m0 + (wave & 1) * 64;
  #pragma unroll
  for (int mt = 0; mt < 4; mt++)
    #pragma unroll
    for (int nt = 0; nt < 4; nt++)
      #pragma unroll
      for (int r = 0; r < 4; r++)
        out[(size_t)(mbase + mt*16 + quad*4 + r)*DIM + ncol + nt*16 + l16] = acc[mt][nt][r];
}

extern "C" void kernel_launch(void* const* d_in, const int* in_sizes, int n_in,
                              void* d_out, int out_size, void* d_ws, size_t ws_size,
                              hipStream_t stream) {
  const float* x     = (const float*)d_in[0];
  const float* scale = (const float*)d_in[1];
  const float* Wq    = (const float*)d_in[2];
  const float* Wk    = (const float*)d_in[3];
  const float* Wv    = (const float*)d_in[4];
  const float* Wo    = (const float*)d_in[5];
  float* out = (float*)d_out;

  const size_t ROWS = (size_t)BATCH * S_LEN;   // 8192
  char* ws = (char*)d_ws;
  f16* xn     = (f16*)ws;  ws += ROWS * DIM * sizeof(f16);            // 8 MB (reused as ao)
  f16* wt_qkv = (f16*)ws;  ws += (size_t)3 * DIM * DIM * sizeof(f16); // 1.5 MB
  f16* wo_t   = (f16*)ws;  ws += (size_t)DIM * DIM * sizeof(f16);     // 0.5 MB
  f16* qb     = (f16*)ws;  ws += (size_t)BHDIM * S_LEN * DH * sizeof(f16); // 8 MB
  f16* kb     = (f16*)ws;  ws += (size_t)BHDIM * S_LEN * DH * sizeof(f16); // 8 MB
  f16* vt     = (f16*)ws;  ws += (size_t)BHDIM * S_LEN * DH * sizeof(f16); // 8 MB
  float* ctab = (float*)ws; ws += (size_t)S_LEN * 32 * sizeof(float);  // 0.5 MB
  float* stab = (float*)ws; ws += (size_t)S_LEN * 32 * sizeof(float);  // 0.5 MB
  f16* po     = (f16*)ws;  ws += (size_t)2 * ROWS2 * DH * sizeof(f16); // 16.8 MB
  float* pm   = (float*)ws; ws += (size_t)2 * ROWS2 * sizeof(float);   // 0.5 MB
  float* pl   = (float*)ws; ws += (size_t)2 * ROWS2 * sizeof(float);   // 0.5 MB
  f16* ao     = xn;  // overlay: xn dead after qkv_gemm

  size_t need = (size_t)(ws - (char*)d_ws);
  if (ws_size < need) return;

  prep_kernel    <<<9728, 256, 0, stream>>>(x, scale, Wq, Wk, Wv, Wo,
                                            xn, wt_qkv, wo_t, ctab, stab);
  qkv_gemm_kernel<<<dim3(64,12), 256, 0, stream>>>(xn, wt_qkv, ctab, stab, qb, kb, vt);
  attn_kernel    <<<1024, 512, 0, stream>>>(qb, kb, vt, po, pm, pl);
  merge_kernel   <<<1024, 256, 0, stream>>>(po, pm, pl, ao);
  out_gemm_kernel<<<dim3(64,4), 256, 0, stream>>>(ao, wo_t, out);
}

// Round 16
// 194.565 us; speedup vs baseline: 6.1012x; 6.1012x over previous
//
#include <hip/hip_runtime.h>
#include <hip/hip_bf16.h>

typedef _Float16 f16;
typedef _Float16 f16x2 __attribute__((ext_vector_type(2)));
typedef _Float16 f16x4 __attribute__((ext_vector_type(4)));
typedef _Float16 f16x8 __attribute__((ext_vector_type(8)));
typedef float f32x4 __attribute__((ext_vector_type(4)));

#define S_LEN 4096
#define DIM   512
#define NH    8
#define DH    64
#define BATCH 2
#define BHDIM (BATCH*NH)   // 16
#define ROWS2 (BHDIM*S_LEN) // 65536

// Q pre-scale: 1/sqrt(64) * log2(e)  (softmax done in exp2 domain)
#define QSCALE 0.18033688011112042f

__device__ __forceinline__ void gld16(const f16* g, f16* l) {
#if __has_builtin(__builtin_amdgcn_global_load_lds)
  __builtin_amdgcn_global_load_lds((const __attribute__((address_space(1))) void*)g,
                                   (__attribute__((address_space(3))) void*)l, 16, 0, 0);
#else
  *(f16x8*)l = *(const f16x8*)g;
#endif
}

__device__ __forceinline__ float fexp2(float x) {
#if __has_builtin(__builtin_amdgcn_exp2f)
  return __builtin_amdgcn_exp2f(x);
#else
  return exp2f(x);
#endif
}

__device__ __forceinline__ f16x2 pk2(float a, float b) {
#if __has_builtin(__builtin_amdgcn_cvt_pkrtz)
  auto r = __builtin_amdgcn_cvt_pkrtz(a, b);   // __fp16 ext_vector(2); same bits
  f16x2 o; __builtin_memcpy(&o, &r, sizeof(o));
  return o;
#else
  f16x2 r; r[0] = (f16)a; r[1] = (f16)b; return r;
#endif
}

// ---------------- Fused prep: rmsnorm + weight transpose + rope tables ----------------
// blocks [0,8192): RMSNorm row; [8192,9216): transpose 32x32 tile; [9216,9728): rope.
__global__ __launch_bounds__(256) void prep_kernel(
    const float* __restrict__ x, const float* __restrict__ scale,
    const float* __restrict__ Wq, const float* __restrict__ Wk,
    const float* __restrict__ Wv, const float* __restrict__ Wo,
    f16* __restrict__ xn, f16* __restrict__ wt_qkv, f16* __restrict__ wo_t,
    float* __restrict__ ctab, float* __restrict__ stab) {
  int bid = blockIdx.x;
  int tid = threadIdx.x;
  if (bid < 8192) {                      // ---- RMSNorm ----
    const float* xr = x + (size_t)bid * DIM;
    float2 v = *(const float2*)(xr + tid*2);
    float ss = v.x*v.x + v.y*v.y;
    #pragma unroll
    for (int off = 32; off > 0; off >>= 1) ss += __shfl_down(ss, off);
    __shared__ float red[4];
    if ((tid & 63) == 0) red[tid >> 6] = ss;
    __syncthreads();
    float tot = red[0] + red[1] + red[2] + red[3];
    float inv = rsqrtf(tot * (1.0f/DIM) + 1e-6f);
    float2 s = *(const float2*)(scale + tid*2);
    xn[(size_t)bid*DIM + tid*2+0] = (f16)(v.x*inv*s.x);
    xn[(size_t)bid*DIM + tid*2+1] = (f16)(v.y*inv*s.y);
  } else if (bid < 9216) {               // ---- weight transpose (f32 -> f16^T) ----
    __shared__ f16 tile[32][33];
    int b2 = bid - 8192;
    int mat = b2 >> 8;                   // 256 blocks per matrix
    int rem = b2 & 255;
    int k0 = (rem >> 4) * 32, n0 = (rem & 15) * 32;
    const float* src = (mat == 0) ? Wq : (mat == 1) ? Wk : (mat == 2) ? Wv : Wo;
    f16* dst = (mat < 3) ? (wt_qkv + (size_t)mat*DIM*DIM) : wo_t;
    int tx = tid & 31, ty = tid >> 5;    // (32, 8)
    #pragma unroll
    for (int i = 0; i < 32; i += 8)
      tile[ty+i][tx] = (f16)src[(size_t)(k0+ty+i)*DIM + n0+tx];
    __syncthreads();
    #pragma unroll
    for (int i = 0; i < 32; i += 8)
      dst[(size_t)(n0+ty+i)*DIM + k0+tx] = tile[tx][ty+i];
  } else {                               // ---- rope cos/sin tables ----
    int idx = (bid - 9216)*256 + tid;    // 0..131071
    int t = idx >> 5, d = idx & 31;
    float theta = exp2f(-(float)d * (19.931568569324174f / 32.0f));
    float sv, cv;
    sincosf((float)t * theta, &sv, &cv);
    ctab[idx] = cv; stab[idx] = sv;
  }
}

// ------------- m97-style 128x128 GEMM core: C = A[M,512] * Bt[N,512]^T -------------
__device__ __forceinline__ void gemm128_acc(
    const f16* __restrict__ A, const f16* __restrict__ Bt,
    int m0, int n0, f16* As, f16* Bs, f32x4 (&acc)[4][4]) {
  const int tid = threadIdx.x;
  const int wave = tid >> 6, lane = tid & 63;
  const int l16 = lane & 15, quad = lane >> 4;
  const int mrow = (wave & 1) * 64, ncol = (wave >> 1) * 64;
  const int srow = tid >> 3;                    // 0..31
  const int gc = (tid & 7) ^ ((tid >> 3) & 7);  // swizzled source chunk

  for (int k0 = 0; k0 < DIM; k0 += 64) {
    if (k0) __syncthreads();
    #pragma unroll
    for (int i = 0; i < 4; i++) {
      gld16(A  + (size_t)(m0 + i*32 + srow)*DIM + k0 + gc*8, As + i*2048 + tid*8);
      gld16(Bt + (size_t)(n0 + i*32 + srow)*DIM + k0 + gc*8, Bs + i*2048 + tid*8);
    }
    __syncthreads();
    #pragma unroll
    for (int kc = 0; kc < 2; kc++) {
      f16x8 a[4], b[4];
      #pragma unroll
      for (int mt = 0; mt < 4; mt++) {
        int row = mrow + mt*16 + l16;
        a[mt] = *(const f16x8*)(As + row*64 + (((quad + 4*kc) ^ (l16 & 7)) * 8));
      }
      #pragma unroll
      for (int nt = 0; nt < 4; nt++) {
        int row = ncol + nt*16 + l16;
        b[nt] = *(const f16x8*)(Bs + row*64 + (((quad + 4*kc) ^ (l16 & 7)) * 8));
      }
      #pragma unroll
      for (int mt = 0; mt < 4; mt++)
        #pragma unroll
        for (int nt = 0; nt < 4; nt++)
          acc[mt][nt] = __builtin_amdgcn_mfma_f32_16x16x32_f16(a[mt], b[nt], acc[mt][nt], 0, 0, 0);
    }
  }
}

// ------------- QKV GEMM + table-RoPE + Q prescale -------------
// V output layout: within each 64-token group, token at permuted position
// pos = ((mt>>1)*4 + quad)*8 + (mt&1)*4 + r  so the attn PV fragment for
// (chunk c, quad) is ONE contiguous f16x8 matching the in-register P order
// sigma(c,quad,j) = (2c + (j>>2))*16 + quad*4 + (j&3).  [verified r9-r15]
__global__ __launch_bounds__(256) void qkv_gemm_kernel(
    const f16* __restrict__ xn, const f16* __restrict__ wt,
    const float* __restrict__ ctab, const float* __restrict__ stab,
    f16* __restrict__ qbuf, f16* __restrict__ kbuf, f16* __restrict__ vt) {
  __shared__ __align__(16) f16 As[128*64], Bs[128*64];
  int m0 = blockIdx.x * 128, n0 = blockIdx.y * 128;
  f32x4 acc[4][4] = {};
  gemm128_acc(xn, wt, m0, n0, As, Bs, acc);

  const int tid = threadIdx.x;
  const int wave = tid >> 6, lane = tid & 63;
  const int l16 = lane & 15, quad = lane >> 4;
  int ncol = n0 + (wave >> 1) * 64;      // head-aligned
  int which = ncol >> 9;                 // 0=q 1=k 2=v (wave-uniform)
  int head = (ncol >> 6) & 7;
  int mbase = m0 + (wave & 1) * 64;

  if (which <= 1) {                      // fused RoPE from tables
    #pragma unroll
    for (int mt = 0; mt < 4; mt++)
      #pragma unroll
      for (int nt = 0; nt < 2; nt++) {
        int d = nt*16 + l16;
        #pragma unroll
        for (int r = 0; r < 4; r++) {
          int t = (mbase + mt*16 + quad*4 + r) & 4095;
          float cv = ctab[t*32 + d], sv = stab[t*32 + d];
          float x1 = acc[mt][nt][r], x2 = acc[mt][nt+2][r];
          acc[mt][nt][r]   = x1*cv - x2*sv;
          acc[mt][nt+2][r] = x1*sv + x2*cv;
        }
      }
  }
  if (which < 2) {
    float osc = (which == 0) ? QSCALE : 1.0f;
    f16* dst = which ? kbuf : qbuf;
    #pragma unroll
    for (int mt = 0; mt < 4; mt++)
      #pragma unroll
      for (int nt = 0; nt < 4; nt++)
        #pragma unroll
        for (int r = 0; r < 4; r++) {
          int m = mbase + mt*16 + quad*4 + r;
          int b = m >> 12, t = m & 4095;
          dst[(((size_t)(b*NH + head))*S_LEN + t)*DH + nt*16 + l16] = (f16)(acc[mt][nt][r]*osc);
        }
  } else {                               // V transposed + pi-permuted token order
    #pragma unroll
    for (int mt = 0; mt < 4; mt++)
      #pragma unroll
      for (int nt = 0; nt < 4; nt++) {
        int m = mbase + mt*16 + quad*4;
        int b = m >> 12, tcol = m & 4095;
        int grp = tcol & ~63;
        int pos = ((mt >> 1)*4 + quad)*8 + (mt & 1)*4;
        int d = nt*16 + l16;
        f16x4 v4 = {(f16)acc[mt][nt][0], (f16)acc[mt][nt][1],
                    (f16)acc[mt][nt][2], (f16)acc[mt][nt][3]};
        *(f16x4*)(vt + ((size_t)((b*NH + head)*DH + d))*S_LEN + grp + pos) = v4;
      }
  }
}

// ------------- Flash attention (causal), 4-band 8-wave blocks + split-K parity -------------
// 1024 blocks x 512 threads. Block = (p2, hf, bh) covering FOUR bands
// {127-p2, 64+p2, 63-p2, p2} whose tile counts sum to a constant 130 for every
// p2 (exact compute balance). Wave w: band bi = w>>1, 16-row half w&1.
// Each staged 64-key tile feeds 4 bands; 4 blocks/CU (threads-capped) x 8 waves
// = 32 waves/CU. NO waves/EU hint: r15's (512,8) clamped VGPR to 32 and spilled
// ~4GB scratch (as did r5/r6). Unconstrained, body allocates ~44-50 VGPR and
// 8 waves/SIMD remain feasible.
__global__ __launch_bounds__(512) void attn_kernel(
    const f16* __restrict__ qbuf, const f16* __restrict__ kbuf,
    const f16* __restrict__ vtb, f16* __restrict__ po,
    float* __restrict__ pm, float* __restrict__ pl) {
  int bid = blockIdx.x;                  // 0..1023
  int bh  = bid & 15;
  int hf  = (bid >> 4) & 1;              // KV-tile parity half
  int p2  = bid >> 5;                    // 0..31

  int tid = threadIdx.x;
  int wave = tid >> 6, lane = tid & 63;
  int l16 = lane & 15, quad = lane >> 4;
  int bi = wave >> 1, half = wave & 1;

  const f16* Q = qbuf + (size_t)bh*S_LEN*DH;
  const f16* K = kbuf + (size_t)bh*S_LEN*DH;
  const f16* V = vtb  + (size_t)bh*DH*S_LEN;   // [dh][s], pi-permuted in s

  // 4 bands partition [0,128): {127-p2 | 96..127, 64+p2 | 64..95, 63-p2 | 32..63, p2 | 0..31}
  int bv = (bi == 0) ? (127 - p2) : (bi == 1) ? (64 + p2)
         : (bi == 2) ? (63 - p2)  : p2;
  int tc = (bv >> 1) + 1;                // this band's KV-tile count
  int T0 = ((127 - p2) >> 1) + 1;        // block loop basis (heaviest band)
  int nloc = (T0 - hf + 1) >> 1;         // this parity's loop count
  int rbase = bv*32 + half*16;           // wave's 16 q-rows

  // Q fragments (B-operand of S^T = K Q^T)
  f16x8 qa0, qa1;
  {
    const f16* qrow = Q + (size_t)(rbase + l16)*DH + quad*8;
    qa0 = *(const f16x8*)(qrow);
    qa1 = *(const f16x8*)(qrow + 32);
  }

  f32x4 o[4] = {};                       // O C-layout [qrow=quad*4+r][dh=dnt*16+l16]
  float m_i = -1e30f;
  float l_i = 0.f;                       // per-lane partial (this quad); reduced in epilogue

  // K [2 bufs][64 kv][64 dh], V [2 bufs][64 dh][64 kv(perm)]  (32 KB)
  __shared__ __align__(16) f16 kt[2*4096];
  __shared__ __align__(16) f16 vs[2*4096];

  const int srow = tid >> 3;                     // 0..63
  const int gcs = (tid & 7) ^ (srow & 7);        // swizzled source chunk

  #define STAGE(buf, kv)                                                        \
    do {                                                                        \
      f16* ktb = kt + (buf)*4096;                                               \
      f16* vsb = vs + (buf)*4096;                                               \
      gld16(K + (size_t)((kv) + srow)*DH + gcs*8, ktb + tid*8);                 \
      gld16(V + (size_t)srow*S_LEN + (kv) + gcs*8, vsb + tid*8);                \
    } while (0)

  STAGE(0, hf*64);
  __syncthreads();                       // drains vmcnt -> first tile staged

  for (int itl = 0; itl < nloc; ++itl) {
    int g = 2*itl + hf;
    int kv0 = g * 64;
    int cur = itl & 1;
    if (itl + 1 < nloc) STAGE(cur ^ 1, kv0 + 128);   // async prefetch next parity tile

    const f16* ktc = kt + cur*4096;
    const f16* vsc = vs + cur*4096;

    if (g < tc) {                        // wave-uniform: this band still active
      bool diag = (g == tc - 1);
      int ntl = diag ? ((bv & 1) ? 4 : 2) : 4;    // live 16-key frags
      int kcl = ntl >> 1;                         // live 32-key chunks

      // ---- S^T = K Q^T ----
      f32x4 st[4];
      #pragma unroll
      for (int nt = 0; nt < 4; nt++) {
        if (nt >= ntl) continue;
        int row = nt*16 + l16;
        f16x8 kf0 = *(const f16x8*)(ktc + row*64 + (((quad)     ^ (row & 7))*8));
        f16x8 kf1 = *(const f16x8*)(ktc + row*64 + (((quad + 4) ^ (row & 7))*8));
        f32x4 z = {};
        z = __builtin_amdgcn_mfma_f32_16x16x32_f16(kf0, qa0, z, 0, 0, 0);
        st[nt] = __builtin_amdgcn_mfma_f32_16x16x32_f16(kf1, qa1, z, 0, 0, 0);
      }

      // ---- softmax (per q-row l16, replicated over quads) ----
      int qglob = rbase + l16;
      float rmx = -1e30f;
      #pragma unroll
      for (int nt = 0; nt < 4; nt++) {
        if (nt >= ntl) continue;
        if (diag) {
          int kb = kv0 + nt*16 + quad*4;
          #pragma unroll
          for (int r = 0; r < 4; r++) {
            float v = st[nt][r];
            if (kb + r > qglob) v = -1e30f;
            st[nt][r] = v;
            rmx = fmaxf(rmx, v);
          }
        } else {
          #pragma unroll
          for (int r = 0; r < 4; r++) rmx = fmaxf(rmx, st[nt][r]);
        }
      }
      rmx = fmaxf(rmx, __shfl_xor(rmx, 16));
      rmx = fmaxf(rmx, __shfl_xor(rmx, 32));
      // defer-max (T13): skip O-rescale while running max grows < THR=8
      if (!__all(rmx <= m_i + 8.0f)) {
        float mnew = fmaxf(m_i, rmx);
        float alpha = fexp2(m_i - mnew);
        m_i = mnew;
        float al[4];
        #pragma unroll
        for (int r = 0; r < 4; r++) al[r] = __shfl(alpha, quad*4 + r);
        #pragma unroll
        for (int dnt = 0; dnt < 4; dnt++)
          #pragma unroll
          for (int r = 0; r < 4; r++) o[dnt][r] *= al[r];
        l_i *= alpha;
      }
      float mref = m_i;
      float rs = 0.f;
      f16x8 pa[2];
      #pragma unroll
      for (int c = 0; c < 2; c++) {
        if (c >= kcl) continue;
        float e0 = fexp2(st[2*c  ][0] - mref);
        float e1 = fexp2(st[2*c  ][1] - mref);
        float e2 = fexp2(st[2*c  ][2] - mref);
        float e3 = fexp2(st[2*c  ][3] - mref);
        float e4 = fexp2(st[2*c+1][0] - mref);
        float e5 = fexp2(st[2*c+1][1] - mref);
        float e6 = fexp2(st[2*c+1][2] - mref);
        float e7 = fexp2(st[2*c+1][3] - mref);
        rs += ((e0+e1)+(e2+e3)) + ((e4+e5)+(e6+e7));
        f16x4 h0 = __builtin_shufflevector(pk2(e0,e1), pk2(e2,e3), 0,1,2,3);
        f16x4 h1 = __builtin_shufflevector(pk2(e4,e5), pk2(e6,e7), 0,1,2,3);
        pa[c] = __builtin_shufflevector(h0, h1, 0,1,2,3,4,5,6,7);
      }
      l_i += rs;

      // ---- PV: one b128 V read per fragment (perm layout) ----
      #pragma unroll
      for (int c = 0; c < 2; c++) {
        if (c >= kcl) continue;
        #pragma unroll
        for (int dnt = 0; dnt < 4; dnt++) {
          int vr = dnt*16 + l16;
          f16x8 vf = *(const f16x8*)(vsc + vr*64 + (((c*4 + quad) ^ (vr & 7))*8));
          o[dnt] = __builtin_amdgcn_mfma_f32_16x16x32_f16(pa[c], vf, o[dnt], 0, 0, 0);
        }
      }
    }

    __syncthreads();  // all waves done reading cur; staged loads (vmcnt) drained
  }
  #undef STAGE

  // epilogue: write normalized partials + (m, l) per row
  {
    float lf = l_i;
    lf += __shfl_xor(lf, 16);
    lf += __shfl_xor(lf, 32);            // row-consistent l (indexed by l16)
    if (quad == 0) {                      // one lane per row writes m, l
      int t = rbase + l16;
      pm[(size_t)(hf*BHDIM + bh)*S_LEN + t] = m_i;
      pl[(size_t)(hf*BHDIM + bh)*S_LEN + t] = lf;
    }
    float lr[4];
    #pragma unroll
    for (int r = 0; r < 4; r++) lr[r] = __shfl(lf, quad*4 + r);
    #pragma unroll
    for (int r = 0; r < 4; r++) {
      float invl = (lr[r] > 0.f) ? 1.0f / lr[r] : 0.f;
      int t = rbase + quad*4 + r;
      size_t rowoff = ((size_t)(hf*BHDIM + bh)*S_LEN + t)*DH;
      #pragma unroll
      for (int dnt = 0; dnt < 4; dnt++)
        po[rowoff + dnt*16 + l16] = (f16)(o[dnt][r]*invl);
    }
  }
}

// ------------- Merge split-K halves: ao = w0*po0 + w1*po1 -------------
__global__ __launch_bounds__(256) void merge_kernel(
    const f16* __restrict__ po, const float* __restrict__ pm,
    const float* __restrict__ pl, f16* __restrict__ ao) {
  int idx = blockIdx.x*256 + threadIdx.x;     // 0..262143
  int r_ = idx >> 2, q = idx & 3;             // row, 16-dim quarter
  int bh = r_ >> 12, t = r_ & 4095;
  float m0 = pm[r_], m1 = pm[ROWS2 + r_];
  float l0 = pl[r_], l1 = pl[ROWS2 + r_];
  float M  = fmaxf(m0, m1);
  float a0 = l0 * fexp2(m0 - M);
  float a1 = l1 * fexp2(m1 - M);
  float inv = 1.0f / (a0 + a1);
  float w0 = a0 * inv, w1 = a1 * inv;
  const f16* p0 = po + (size_t)r_*DH + q*16;
  const f16* p1 = po + (size_t)(ROWS2 + r_)*DH + q*16;
  int b = bh >> 3, h = bh & 7;
  f16* dst = ao + ((size_t)(b*S_LEN + t))*DIM + h*DH + q*16;
  f16x8 v0a = *(const f16x8*)(p0), v0b = *(const f16x8*)(p0 + 8);
  f16x8 v1a = *(const f16x8*)(p1), v1b = *(const f16x8*)(p1 + 8);
  f16x8 oa, ob;
  #pragma unroll
  for (int j = 0; j < 8; j++) {
    oa[j] = (f16)(w0*(float)v0a[j] + w1*(float)v1a[j]);
    ob[j] = (f16)(w0*(float)v0b[j] + w1*(float)v1b[j]);
  }
  *(f16x8*)dst = oa;
  *(f16x8*)(dst + 8) = ob;
}

// ------------- Output GEMM: ao[8192,512] @ Wo -> out f32 -------------
__global__ __launch_bounds__(256) void out_gemm_kernel(
    const f16* __restrict__ ao, const f16* __restrict__ wot,
    float* __restrict__ out) {
  __shared__ __align__(16) f16 As[128*64], Bs[128*64];
  int m0 = blockIdx.x * 128, n0 = blockIdx.y * 128;
  f32x4 acc[4][4] = {};
  gemm128_acc(ao, wot, m0, n0, As, Bs, acc);

  const int tid = threadIdx.x;
  const int wave = tid >> 6, lane = tid & 63;
  const int l16 = lane & 15, quad = lane >> 4;
  int ncol = n0 + (wave >> 1) * 64;
  int mbase = m0 + (wave & 1) * 64;
  #pragma unroll
  for (int mt = 0; mt < 4; mt++)
    #pragma unroll
    for (int nt = 0; nt < 4; nt++)
      #pragma unroll
      for (int r = 0; r < 4; r++)
        out[(size_t)(mbase + mt*16 + quad*4 + r)*DIM + ncol + nt*16 + l16] = acc[mt][nt][r];
}

extern "C" void kernel_launch(void* const* d_in, const int* in_sizes, int n_in,
                              void* d_out, int out_size, void* d_ws, size_t ws_size,
                              hipStream_t stream) {
  const float* x     = (const float*)d_in[0];
  const float* scale = (const float*)d_in[1];
  const float* Wq    = (const float*)d_in[2];
  const float* Wk    = (const float*)d_in[3];
  const float* Wv    = (const float*)d_in[4];
  const float* Wo    = (const float*)d_in[5];
  float* out = (float*)d_out;

  const size_t ROWS = (size_t)BATCH * S_LEN;   // 8192
  char* ws = (char*)d_ws;
  f16* xn     = (f16*)ws;  ws += ROWS * DIM * sizeof(f16);            // 8 MB (reused as ao)
  f16* wt_qkv = (f16*)ws;  ws += (size_t)3 * DIM * DIM * sizeof(f16); // 1.5 MB
  f16* wo_t   = (f16*)ws;  ws += (size_t)DIM * DIM * sizeof(f16);     // 0.5 MB
  f16* qb     = (f16*)ws;  ws += (size_t)BHDIM * S_LEN * DH * sizeof(f16); // 8 MB
  f16* kb     = (f16*)ws;  ws += (size_t)BHDIM * S_LEN * DH * sizeof(f16); // 8 MB
  f16* vt     = (f16*)ws;  ws += (size_t)BHDIM * S_LEN * DH * sizeof(f16); // 8 MB
  float* ctab = (float*)ws; ws += (size_t)S_LEN * 32 * sizeof(float);  // 0.5 MB
  float* stab = (float*)ws; ws += (size_t)S_LEN * 32 * sizeof(float);  // 0.5 MB
  f16* po     = (f16*)ws;  ws += (size_t)2 * ROWS2 * DH * sizeof(f16); // 16.8 MB
  float* pm   = (float*)ws; ws += (size_t)2 * ROWS2 * sizeof(float);   // 0.5 MB
  float* pl   = (float*)ws; ws += (size_t)2 * ROWS2 * sizeof(float);   // 0.5 MB
  f16* ao     = xn;  // overlay: xn dead after qkv_gemm

  size_t need = (size_t)(ws - (char*)d_ws);
  if (ws_size < need) return;

  prep_kernel    <<<9728, 256, 0, stream>>>(x, scale, Wq, Wk, Wv, Wo,
                                            xn, wt_qkv, wo_t, ctab, stab);
  qkv_gemm_kernel<<<dim3(64,12), 256, 0, stream>>>(xn, wt_qkv, ctab, stab, qb, kb, vt);
  attn_kernel    <<<1024, 512, 0, stream>>>(qb, kb, vt, po, pm, pl);
  merge_kernel   <<<1024, 256, 0, stream>>>(po, pm, pl, ao);
  out_gemm_kernel<<<dim3(64,4), 256, 0, stream>>>(ao, wo_t, out);
}

// Round 17
// 192.079 us; speedup vs baseline: 6.1801x; 1.0129x over previous
//
#include <hip/hip_runtime.h>
#include <hip/hip_bf16.h>

typedef _Float16 f16;
typedef _Float16 f16x2 __attribute__((ext_vector_type(2)));
typedef _Float16 f16x4 __attribute__((ext_vector_type(4)));
typedef _Float16 f16x8 __attribute__((ext_vector_type(8)));
typedef float f32x4 __attribute__((ext_vector_type(4)));

#define S_LEN 4096
#define DIM   512
#define NH    8
#define DH    64
#define BATCH 2
#define BHDIM (BATCH*NH)   // 16
#define ROWS2 (BHDIM*S_LEN) // 65536

// Q pre-scale: 1/sqrt(64) * log2(e)  (softmax done in exp2 domain)
#define QSCALE 0.18033688011112042f

__device__ __forceinline__ void gld16(const f16* g, f16* l) {
#if __has_builtin(__builtin_amdgcn_global_load_lds)
  __builtin_amdgcn_global_load_lds((const __attribute__((address_space(1))) void*)g,
                                   (__attribute__((address_space(3))) void*)l, 16, 0, 0);
#else
  *(f16x8*)l = *(const f16x8*)g;
#endif
}

__device__ __forceinline__ float fexp2(float x) {
#if __has_builtin(__builtin_amdgcn_exp2f)
  return __builtin_amdgcn_exp2f(x);
#else
  return exp2f(x);
#endif
}

__device__ __forceinline__ f16x2 pk2(float a, float b) {
#if __has_builtin(__builtin_amdgcn_cvt_pkrtz)
  auto r = __builtin_amdgcn_cvt_pkrtz(a, b);   // __fp16 ext_vector(2); same bits
  f16x2 o; __builtin_memcpy(&o, &r, sizeof(o));
  return o;
#else
  f16x2 r; r[0] = (f16)a; r[1] = (f16)b; return r;
#endif
}

// ---------------- Fused prep: rmsnorm + weight transpose + rope tables ----------------
// blocks [0,8192): RMSNorm row; [8192,9216): transpose 32x32 tile; [9216,9728): rope.
__global__ __launch_bounds__(256) void prep_kernel(
    const float* __restrict__ x, const float* __restrict__ scale,
    const float* __restrict__ Wq, const float* __restrict__ Wk,
    const float* __restrict__ Wv, const float* __restrict__ Wo,
    f16* __restrict__ xn, f16* __restrict__ wt_qkv, f16* __restrict__ wo_t,
    float* __restrict__ ctab, float* __restrict__ stab) {
  int bid = blockIdx.x;
  int tid = threadIdx.x;
  if (bid < 8192) {                      // ---- RMSNorm ----
    const float* xr = x + (size_t)bid * DIM;
    float2 v = *(const float2*)(xr + tid*2);
    float ss = v.x*v.x + v.y*v.y;
    #pragma unroll
    for (int off = 32; off > 0; off >>= 1) ss += __shfl_down(ss, off);
    __shared__ float red[4];
    if ((tid & 63) == 0) red[tid >> 6] = ss;
    __syncthreads();
    float tot = red[0] + red[1] + red[2] + red[3];
    float inv = rsqrtf(tot * (1.0f/DIM) + 1e-6f);
    float2 s = *(const float2*)(scale + tid*2);
    xn[(size_t)bid*DIM + tid*2+0] = (f16)(v.x*inv*s.x);
    xn[(size_t)bid*DIM + tid*2+1] = (f16)(v.y*inv*s.y);
  } else if (bid < 9216) {               // ---- weight transpose (f32 -> f16^T) ----
    __shared__ f16 tile[32][33];
    int b2 = bid - 8192;
    int mat = b2 >> 8;                   // 256 blocks per matrix
    int rem = b2 & 255;
    int k0 = (rem >> 4) * 32, n0 = (rem & 15) * 32;
    const float* src = (mat == 0) ? Wq : (mat == 1) ? Wk : (mat == 2) ? Wv : Wo;
    f16* dst = (mat < 3) ? (wt_qkv + (size_t)mat*DIM*DIM) : wo_t;
    int tx = tid & 31, ty = tid >> 5;    // (32, 8)
    #pragma unroll
    for (int i = 0; i < 32; i += 8)
      tile[ty+i][tx] = (f16)src[(size_t)(k0+ty+i)*DIM + n0+tx];
    __syncthreads();
    #pragma unroll
    for (int i = 0; i < 32; i += 8)
      dst[(size_t)(n0+ty+i)*DIM + k0+tx] = tile[tx][ty+i];
  } else {                               // ---- rope cos/sin tables ----
    int idx = (bid - 9216)*256 + tid;    // 0..131071
    int t = idx >> 5, d = idx & 31;
    float theta = exp2f(-(float)d * (19.931568569324174f / 32.0f));
    float sv, cv;
    sincosf((float)t * theta, &sv, &cv);
    ctab[idx] = cv; stab[idx] = sv;
  }
}

// ------------- m97-style 128x128 GEMM core: C = A[M,512] * Bt[N,512]^T -------------
__device__ __forceinline__ void gemm128_acc(
    const f16* __restrict__ A, const f16* __restrict__ Bt,
    int m0, int n0, f16* As, f16* Bs, f32x4 (&acc)[4][4]) {
  const int tid = threadIdx.x;
  const int wave = tid >> 6, lane = tid & 63;
  const int l16 = lane & 15, quad = lane >> 4;
  const int mrow = (wave & 1) * 64, ncol = (wave >> 1) * 64;
  const int srow = tid >> 3;                    // 0..31
  const int gc = (tid & 7) ^ ((tid >> 3) & 7);  // swizzled source chunk

  for (int k0 = 0; k0 < DIM; k0 += 64) {
    if (k0) __syncthreads();
    #pragma unroll
    for (int i = 0; i < 4; i++) {
      gld16(A  + (size_t)(m0 + i*32 + srow)*DIM + k0 + gc*8, As + i*2048 + tid*8);
      gld16(Bt + (size_t)(n0 + i*32 + srow)*DIM + k0 + gc*8, Bs + i*2048 + tid*8);
    }
    __syncthreads();
    #pragma unroll
    for (int kc = 0; kc < 2; kc++) {
      f16x8 a[4], b[4];
      #pragma unroll
      for (int mt = 0; mt < 4; mt++) {
        int row = mrow + mt*16 + l16;
        a[mt] = *(const f16x8*)(As + row*64 + (((quad + 4*kc) ^ (l16 & 7)) * 8));
      }
      #pragma unroll
      for (int nt = 0; nt < 4; nt++) {
        int row = ncol + nt*16 + l16;
        b[nt] = *(const f16x8*)(Bs + row*64 + (((quad + 4*kc) ^ (l16 & 7)) * 8));
      }
      #pragma unroll
      for (int mt = 0; mt < 4; mt++)
        #pragma unroll
        for (int nt = 0; nt < 4; nt++)
          acc[mt][nt] = __builtin_amdgcn_mfma_f32_16x16x32_f16(a[mt], b[nt], acc[mt][nt], 0, 0, 0);
    }
  }
}

// ------------- QKV GEMM + table-RoPE + Q prescale, LDS-staged coalesced epilogue -------------
// V output layout: within each 64-token group, token at permuted position
// pos = ((mt>>1)*4 + quad)*8 + (mt&1)*4 + r  (verified r9-r16).
// NEW r17: epilogue stages each wave's 64x64 tile into its 8KB quarter of As/Bs
// (chunk-XOR swizzled), then writes out contiguously: Q/K rows are 128B-adjacent
// -> 1KB contiguous per instruction (was 2B scatter); V written as 128B segments
// per d-row in sigma-permuted form (was 8B scatter at 8KB stride).
__global__ __launch_bounds__(256) void qkv_gemm_kernel(
    const f16* __restrict__ xn, const f16* __restrict__ wt,
    const float* __restrict__ ctab, const float* __restrict__ stab,
    f16* __restrict__ qbuf, f16* __restrict__ kbuf, f16* __restrict__ vt) {
  __shared__ __align__(16) f16 As[128*64], Bs[128*64];
  int m0 = blockIdx.x * 128, n0 = blockIdx.y * 128;
  f32x4 acc[4][4] = {};
  gemm128_acc(xn, wt, m0, n0, As, Bs, acc);

  const int tid = threadIdx.x;
  const int wave = tid >> 6, lane = tid & 63;
  const int l16 = lane & 15, quad = lane >> 4;
  int ncol = n0 + (wave >> 1) * 64;      // head-aligned
  int which = ncol >> 9;                 // 0=q 1=k 2=v (wave-uniform)
  int head = (ncol >> 6) & 7;
  int mbase = m0 + (wave & 1) * 64;      // 64-aligned; never crosses b boundary

  if (which <= 1) {                      // fused RoPE from tables
    #pragma unroll
    for (int mt = 0; mt < 4; mt++)
      #pragma unroll
      for (int nt = 0; nt < 2; nt++) {
        int d = nt*16 + l16;
        #pragma unroll
        for (int r = 0; r < 4; r++) {
          int t = (mbase + mt*16 + quad*4 + r) & 4095;
          float cv = ctab[t*32 + d], sv = stab[t*32 + d];
          float x1 = acc[mt][nt][r], x2 = acc[mt][nt+2][r];
          acc[mt][nt][r]   = x1*cv - x2*sv;
          acc[mt][nt+2][r] = x1*sv + x2*cv;
        }
      }
  }

  __syncthreads();                       // all waves done reading As/Bs (gemm)
  f16* stg = (wave < 2) ? (As + wave*4096) : (Bs + (wave-2)*4096);  // 8KB/wave

  if (which < 2) {
    float osc = (which == 0) ? QSCALE : 1.0f;
    // stage [local_t][d], chunk-XOR swizzled within each 128B row
    #pragma unroll
    for (int mt = 0; mt < 4; mt++)
      #pragma unroll
      for (int nt = 0; nt < 4; nt++)
        #pragma unroll
        for (int r = 0; r < 4; r++) {
          int lm = mt*16 + quad*4 + r;
          int ln = nt*16 + l16;
          stg[lm*64 + (((ln >> 3) ^ (lm & 7))*8 + (ln & 7))] = (f16)(acc[mt][nt][r]*osc);
        }
    f16* dst = which ? kbuf : qbuf;
    int b = mbase >> 12, tb = mbase & 4095;
    size_t base = (((size_t)(b*NH + head))*S_LEN + tb)*DH;
    #pragma unroll
    for (int j = 0; j < 8; j++) {        // 1KB contiguous per iteration
      int cc = j*64 + lane;
      int lm = cc >> 3, ic = cc & 7;
      f16x8 v = *(const f16x8*)(stg + lm*64 + ((ic ^ (lm & 7))*8));
      *(f16x8*)(dst + base + (size_t)lm*DH + ic*8) = v;
    }
  } else {
    // stage transposed [d][token pos sigma], chunk-XOR swizzled
    #pragma unroll
    for (int mt = 0; mt < 4; mt++)
      #pragma unroll
      for (int nt = 0; nt < 4; nt++) {
        int posb = ((mt >> 1)*4 + quad)*8 + (mt & 1)*4;
        #pragma unroll
        for (int r = 0; r < 4; r++) {
          int ln = nt*16 + l16;          // d
          int pos = posb + r;            // sigma token position
          stg[ln*64 + (((pos >> 3) ^ (ln & 7))*8 + (pos & 7))] = (f16)acc[mt][nt][r];
        }
      }
    int b = mbase >> 12, grp = mbase & 4095;
    size_t vbase = ((size_t)((b*NH + head))*DH)*S_LEN + grp;
    #pragma unroll
    for (int j = 0; j < 8; j++) {        // 8 x 128B segments per iteration
      int cc = j*64 + lane;
      int d = cc >> 3, ic = cc & 7;
      f16x8 v = *(const f16x8*)(stg + d*64 + ((ic ^ (d & 7))*8));
      *(f16x8*)(vt + vbase + (size_t)d*S_LEN + ic*8) = v;
    }
  }
}

// ------------- Flash attention (causal), band-specialized + split-K parity -------------
// r13 structure verbatim (best measured: 83.0us, occupancy 39%, VGPR 44).
// 2048 blocks x 256 threads. Block = (pair p, parity hf, bh). Wave w owns ONE band
// (bi = w>>1: 0 = heavy 127-p, 1 = light p) and one 16-row half (w&1).
// Block processes only KV tiles g = 2*itl + hf; partials to po/pm/pl; merge combines.
__global__ __launch_bounds__(256, 5) void attn_kernel(
    const f16* __restrict__ qbuf, const f16* __restrict__ kbuf,
    const f16* __restrict__ vtb, f16* __restrict__ po,
    float* __restrict__ pm, float* __restrict__ pl) {
  int bid = blockIdx.x;                  // 0..2047
  int bh  = bid & 15;
  int hf  = (bid >> 4) & 1;              // KV-tile parity half
  int p   = bid >> 5;                    // pair index 0..63

  int tid = threadIdx.x;
  int wave = tid >> 6, lane = tid & 63;
  int l16 = lane & 15, quad = lane >> 4;
  int bi = wave >> 1, half = wave & 1;

  const f16* Q = qbuf + (size_t)bh*S_LEN*DH;
  const f16* K = kbuf + (size_t)bh*S_LEN*DH;
  const f16* V = vtb  + (size_t)bh*DH*S_LEN;   // [dh][s], pi-permuted in s

  int bv = bi ? p : (127 - p);           // this wave's band (32 q-rows)
  int tc = (bv >> 1) + 1;                // its KV-tile count
  int T0 = ((127 - p) >> 1) + 1;         // heavy band tile count (block loop basis)
  int nloc = (T0 - hf + 1) >> 1;         // this parity's loop count
  int rbase = bv*32 + half*16;           // wave's 16 q-rows

  // Q fragments (B-operand of S^T = K Q^T)
  f16x8 qa0, qa1;
  {
    const f16* qrow = Q + (size_t)(rbase + l16)*DH + quad*8;
    qa0 = *(const f16x8*)(qrow);
    qa1 = *(const f16x8*)(qrow + 32);
  }

  f32x4 o[4] = {};                       // O C-layout [qrow=quad*4+r][dh=dnt*16+l16]
  float m_i = -1e30f;
  float l_i = 0.f;                       // per-lane partial (this quad); reduced in epilogue

  // K [2 bufs][64 kv][64 dh], V [2 bufs][64 dh][64 kv(perm)]  (32 KB)
  __shared__ __align__(16) f16 kt[2*4096];
  __shared__ __align__(16) f16 vs[2*4096];

  const int srow = tid >> 3;                     // 0..31
  const int gcs = (tid & 7) ^ (srow & 7);        // swizzled source chunk

  #define STAGE(buf, kv)                                                        \
    do {                                                                        \
      f16* ktb = kt + (buf)*4096;                                               \
      f16* vsb = vs + (buf)*4096;                                               \
      _Pragma("unroll")                                                         \
      for (int n = 0; n < 2; n++) {                                             \
        gld16(K + (size_t)((kv) + n*32 + srow)*DH + gcs*8, ktb + n*2048 + tid*8);\
        gld16(V + (size_t)(n*32 + srow)*S_LEN + (kv) + gcs*8, vsb + n*2048 + tid*8);\
      }                                                                         \
    } while (0)

  STAGE(0, hf*64);
  __syncthreads();                       // drains vmcnt -> first tile staged

  for (int itl = 0; itl < nloc; ++itl) {
    int g = 2*itl + hf;
    int kv0 = g * 64;
    int cur = itl & 1;
    if (itl + 1 < nloc) STAGE(cur ^ 1, kv0 + 128);   // async prefetch next parity tile

    const f16* ktc = kt + cur*4096;
    const f16* vsc = vs + cur*4096;

    if (g < tc) {                        // wave-uniform: this band still active
      bool diag = (g == tc - 1);
      int ntl = diag ? ((bv & 1) ? 4 : 2) : 4;    // live 16-key frags
      int kcl = ntl >> 1;                         // live 32-key chunks

      // ---- S^T = K Q^T ----
      f32x4 st[4];
      #pragma unroll
      for (int nt = 0; nt < 4; nt++) {
        if (nt >= ntl) continue;
        int row = nt*16 + l16;
        f16x8 kf0 = *(const f16x8*)(ktc + row*64 + (((quad)     ^ (row & 7))*8));
        f16x8 kf1 = *(const f16x8*)(ktc + row*64 + (((quad + 4) ^ (row & 7))*8));
        f32x4 z = {};
        z = __builtin_amdgcn_mfma_f32_16x16x32_f16(kf0, qa0, z, 0, 0, 0);
        st[nt] = __builtin_amdgcn_mfma_f32_16x16x32_f16(kf1, qa1, z, 0, 0, 0);
      }

      // ---- softmax (per q-row l16, replicated over quads) ----
      int qglob = rbase + l16;
      float rmx = -1e30f;
      #pragma unroll
      for (int nt = 0; nt < 4; nt++) {
        if (nt >= ntl) continue;
        if (diag) {
          int kb = kv0 + nt*16 + quad*4;
          #pragma unroll
          for (int r = 0; r < 4; r++) {
            float v = st[nt][r];
            if (kb + r > qglob) v = -1e30f;
            st[nt][r] = v;
            rmx = fmaxf(rmx, v);
          }
        } else {
          #pragma unroll
          for (int r = 0; r < 4; r++) rmx = fmaxf(rmx, st[nt][r]);
        }
      }
      rmx = fmaxf(rmx, __shfl_xor(rmx, 16));
      rmx = fmaxf(rmx, __shfl_xor(rmx, 32));
      // defer-max (T13): skip O-rescale while running max grows < THR=8
      if (!__all(rmx <= m_i + 8.0f)) {
        float mnew = fmaxf(m_i, rmx);
        float alpha = fexp2(m_i - mnew);
        m_i = mnew;
        float al[4];
        #pragma unroll
        for (int r = 0; r < 4; r++) al[r] = __shfl(alpha, quad*4 + r);
        #pragma unroll
        for (int dnt = 0; dnt < 4; dnt++)
          #pragma unroll
          for (int r = 0; r < 4; r++) o[dnt][r] *= al[r];
        l_i *= alpha;
      }
      float mref = m_i;
      float rs = 0.f;
      f16x8 pa[2];
      #pragma unroll
      for (int c = 0; c < 2; c++) {
        if (c >= kcl) continue;
        float e0 = fexp2(st[2*c  ][0] - mref);
        float e1 = fexp2(st[2*c  ][1] - mref);
        float e2 = fexp2(st[2*c  ][2] - mref);
        float e3 = fexp2(st[2*c  ][3] - mref);
        float e4 = fexp2(st[2*c+1][0] - mref);
        float e5 = fexp2(st[2*c+1][1] - mref);
        float e6 = fexp2(st[2*c+1][2] - mref);
        float e7 = fexp2(st[2*c+1][3] - mref);
        rs += ((e0+e1)+(e2+e3)) + ((e4+e5)+(e6+e7));
        f16x4 h0 = __builtin_shufflevector(pk2(e0,e1), pk2(e2,e3), 0,1,2,3);
        f16x4 h1 = __builtin_shufflevector(pk2(e4,e5), pk2(e6,e7), 0,1,2,3);
        pa[c] = __builtin_shufflevector(h0, h1, 0,1,2,3,4,5,6,7);
      }
      l_i += rs;

      // ---- PV: one b128 V read per fragment (perm layout) ----
      #pragma unroll
      for (int c = 0; c < 2; c++) {
        if (c >= kcl) continue;
        #pragma unroll
        for (int dnt = 0; dnt < 4; dnt++) {
          int vr = dnt*16 + l16;
          f16x8 vf = *(const f16x8*)(vsc + vr*64 + (((c*4 + quad) ^ (vr & 7))*8));
          o[dnt] = __builtin_amdgcn_mfma_f32_16x16x32_f16(pa[c], vf, o[dnt], 0, 0, 0);
        }
      }
    }

    __syncthreads();  // all waves done reading cur; staged loads (vmcnt) drained
  }
  #undef STAGE

  // epilogue: write normalized partials + (m, l) per row
  {
    float lf = l_i;
    lf += __shfl_xor(lf, 16);
    lf += __shfl_xor(lf, 32);            // row-consistent l (indexed by l16)
    if (quad == 0) {                      // one lane per row writes m, l
      int t = rbase + l16;
      pm[(size_t)(hf*BHDIM + bh)*S_LEN + t] = m_i;
      pl[(size_t)(hf*BHDIM + bh)*S_LEN + t] = lf;
    }
    float lr[4];
    #pragma unroll
    for (int r = 0; r < 4; r++) lr[r] = __shfl(lf, quad*4 + r);
    #pragma unroll
    for (int r = 0; r < 4; r++) {
      float invl = (lr[r] > 0.f) ? 1.0f / lr[r] : 0.f;
      int t = rbase + quad*4 + r;
      size_t rowoff = ((size_t)(hf*BHDIM + bh)*S_LEN + t)*DH;
      #pragma unroll
      for (int dnt = 0; dnt < 4; dnt++)
        po[rowoff + dnt*16 + l16] = (f16)(o[dnt][r]*invl);
    }
  }
}

// ------------- Merge split-K halves: ao = w0*po0 + w1*po1 -------------
__global__ __launch_bounds__(256) void merge_kernel(
    const f16* __restrict__ po, const float* __restrict__ pm,
    const float* __restrict__ pl, f16* __restrict__ ao) {
  int idx = blockIdx.x*256 + threadIdx.x;     // 0..262143
  int r_ = idx >> 2, q = idx & 3;             // row, 16-dim quarter
  int bh = r_ >> 12, t = r_ & 4095;
  float m0 = pm[r_], m1 = pm[ROWS2 + r_];
  float l0 = pl[r_], l1 = pl[ROWS2 + r_];
  float M  = fmaxf(m0, m1);
  float a0 = l0 * fexp2(m0 - M);
  float a1 = l1 * fexp2(m1 - M);
  float inv = 1.0f / (a0 + a1);
  float w0 = a0 * inv, w1 = a1 * inv;
  const f16* p0 = po + (size_t)r_*DH + q*16;
  const f16* p1 = po + (size_t)(ROWS2 + r_)*DH + q*16;
  int b = bh >> 3, h = bh & 7;
  f16* dst = ao + ((size_t)(b*S_LEN + t))*DIM + h*DH + q*16;
  f16x8 v0a = *(const f16x8*)(p0), v0b = *(const f16x8*)(p0 + 8);
  f16x8 v1a = *(const f16x8*)(p1), v1b = *(const f16x8*)(p1 + 8);
  f16x8 oa, ob;
  #pragma unroll
  for (int j = 0; j < 8; j++) {
    oa[j] = (f16)(w0*(float)v0a[j] + w1*(float)v1a[j]);
    ob[j] = (f16)(w0*(float)v0b[j] + w1*(float)v1b[j]);
  }
  *(f16x8*)dst = oa;
  *(f16x8*)(dst + 8) = ob;
}

// ------------- Output GEMM: ao[8192,512] @ Wo -> out f32 -------------
__global__ __launch_bounds__(256) void out_gemm_kernel(
    const f16* __restrict__ ao, const f16* __restrict__ wot,
    float* __restrict__ out) {
  __shared__ __align__(16) f16 As[128*64], Bs[128*64];
  int m0 = blockIdx.x * 128, n0 = blockIdx.y * 128;
  f32x4 acc[4][4] = {};
  gemm128_acc(ao, wot, m0, n0, As, Bs, acc);

  const int tid = threadIdx.x;
  const int wave = tid >> 6, lane = tid & 63;
  const int l16 = lane & 15, quad = lane >> 4;
  int ncol = n0 + (wave >> 1) * 64;
  int mbase = m0 + (wave & 1) * 64;
  #pragma unroll
  for (int mt = 0; mt < 4; mt++)
    #pragma unroll
    for (int nt = 0; nt < 4; nt++)
      #pragma unroll
      for (int r = 0; r < 4; r++)
        out[(size_t)(mbase + mt*16 + quad*4 + r)*DIM + ncol + nt*16 + l16] = acc[mt][nt][r];
}

extern "C" void kernel_launch(void* const* d_in, const int* in_sizes, int n_in,
                              void* d_out, int out_size, void* d_ws, size_t ws_size,
                              hipStream_t stream) {
  const float* x     = (const float*)d_in[0];
  const float* scale = (const float*)d_in[1];
  const float* Wq    = (const float*)d_in[2];
  const float* Wk    = (const float*)d_in[3];
  const float* Wv    = (const float*)d_in[4];
  const float* Wo    = (const float*)d_in[5];
  float* out = (float*)d_out;

  const size_t ROWS = (size_t)BATCH * S_LEN;   // 8192
  char* ws = (char*)d_ws;
  f16* xn     = (f16*)ws;  ws += ROWS * DIM * sizeof(f16);            // 8 MB (reused as ao)
  f16* wt_qkv = (f16*)ws;  ws += (size_t)3 * DIM * DIM * sizeof(f16); // 1.5 MB
  f16* wo_t   = (f16*)ws;  ws += (size_t)DIM * DIM * sizeof(f16);     // 0.5 MB
  f16* qb     = (f16*)ws;  ws += (size_t)BHDIM * S_LEN * DH * sizeof(f16); // 8 MB
  f16* kb     = (f16*)ws;  ws += (size_t)BHDIM * S_LEN * DH * sizeof(f16); // 8 MB
  f16* vt     = (f16*)ws;  ws += (size_t)BHDIM * S_LEN * DH * sizeof(f16); // 8 MB
  float* ctab = (float*)ws; ws += (size_t)S_LEN * 32 * sizeof(float);  // 0.5 MB
  float* stab = (float*)ws; ws += (size_t)S_LEN * 32 * sizeof(float);  // 0.5 MB
  f16* po     = (f16*)ws;  ws += (size_t)2 * ROWS2 * DH * sizeof(f16); // 16.8 MB
  float* pm   = (float*)ws; ws += (size_t)2 * ROWS2 * sizeof(float);   // 0.5 MB
  float* pl   = (float*)ws; ws += (size_t)2 * ROWS2 * sizeof(float);   // 0.5 MB
  f16* ao     = xn;  // overlay: xn dead after qkv_gemm

  size_t need = (size_t)(ws - (char*)d_ws);
  if (ws_size < need) return;

  prep_kernel    <<<9728, 256, 0, stream>>>(x, scale, Wq, Wk, Wv, Wo,
                                            xn, wt_qkv, wo_t, ctab, stab);
  qkv_gemm_kernel<<<dim3(64,12), 256, 0, stream>>>(xn, wt_qkv, ctab, stab, qb, kb, vt);
  attn_kernel    <<<2048, 256, 0, stream>>>(qb, kb, vt, po, pm, pl);
  merge_kernel   <<<1024, 256, 0, stream>>>(po, pm, pl, ao);
  out_gemm_kernel<<<dim3(64,4), 256, 0, stream>>>(ao, wo_t, out);
}

// Round 18
// 186.527 us; speedup vs baseline: 6.3641x; 1.0298x over previous
//
#include <hip/hip_runtime.h>
#include <hip/hip_bf16.h>

typedef _Float16 f16;
typedef _Float16 f16x2 __attribute__((ext_vector_type(2)));
typedef _Float16 f16x4 __attribute__((ext_vector_type(4)));
typedef _Float16 f16x8 __attribute__((ext_vector_type(8)));
typedef float f32x4 __attribute__((ext_vector_type(4)));

#define S_LEN 4096
#define DIM   512
#define NH    8
#define DH    64
#define BATCH 2
#define BHDIM (BATCH*NH)   // 16
#define ROWS2 (BHDIM*S_LEN) // 65536

// Q pre-scale: 1/sqrt(64) * log2(e)  (softmax done in exp2 domain)
#define QSCALE 0.18033688011112042f

__device__ __forceinline__ void gld16(const f16* g, f16* l) {
#if __has_builtin(__builtin_amdgcn_global_load_lds)
  __builtin_amdgcn_global_load_lds((const __attribute__((address_space(1))) void*)g,
                                   (__attribute__((address_space(3))) void*)l, 16, 0, 0);
#else
  *(f16x8*)l = *(const f16x8*)g;
#endif
}

__device__ __forceinline__ float fexp2(float x) {
#if __has_builtin(__builtin_amdgcn_exp2f)
  return __builtin_amdgcn_exp2f(x);
#else
  return exp2f(x);
#endif
}

__device__ __forceinline__ float fmax3(float a, float b, float c) {
  return fmaxf(fmaxf(a, b), c);          // clang fuses to v_max3_f32
}

__device__ __forceinline__ f16x2 pk2(float a, float b) {
#if __has_builtin(__builtin_amdgcn_cvt_pkrtz)
  auto r = __builtin_amdgcn_cvt_pkrtz(a, b);   // __fp16 ext_vector(2); same bits
  f16x2 o; __builtin_memcpy(&o, &r, sizeof(o));
  return o;
#else
  f16x2 r; r[0] = (f16)a; r[1] = (f16)b; return r;
#endif
}

// ---------------- Fused prep: rmsnorm + weight transpose + rope tables ----------------
// blocks [0,8192): RMSNorm row; [8192,9216): transpose 32x32 tile; [9216,9728): rope.
__global__ __launch_bounds__(256) void prep_kernel(
    const float* __restrict__ x, const float* __restrict__ scale,
    const float* __restrict__ Wq, const float* __restrict__ Wk,
    const float* __restrict__ Wv, const float* __restrict__ Wo,
    f16* __restrict__ xn, f16* __restrict__ wt_qkv, f16* __restrict__ wo_t,
    float* __restrict__ ctab, float* __restrict__ stab) {
  int bid = blockIdx.x;
  int tid = threadIdx.x;
  if (bid < 8192) {                      // ---- RMSNorm ----
    const float* xr = x + (size_t)bid * DIM;
    float2 v = *(const float2*)(xr + tid*2);
    float ss = v.x*v.x + v.y*v.y;
    #pragma unroll
    for (int off = 32; off > 0; off >>= 1) ss += __shfl_down(ss, off);
    __shared__ float red[4];
    if ((tid & 63) == 0) red[tid >> 6] = ss;
    __syncthreads();
    float tot = red[0] + red[1] + red[2] + red[3];
    float inv = rsqrtf(tot * (1.0f/DIM) + 1e-6f);
    float2 s = *(const float2*)(scale + tid*2);
    xn[(size_t)bid*DIM + tid*2+0] = (f16)(v.x*inv*s.x);
    xn[(size_t)bid*DIM + tid*2+1] = (f16)(v.y*inv*s.y);
  } else if (bid < 9216) {               // ---- weight transpose (f32 -> f16^T) ----
    __shared__ f16 tile[32][33];
    int b2 = bid - 8192;
    int mat = b2 >> 8;                   // 256 blocks per matrix
    int rem = b2 & 255;
    int k0 = (rem >> 4) * 32, n0 = (rem & 15) * 32;
    const float* src = (mat == 0) ? Wq : (mat == 1) ? Wk : (mat == 2) ? Wv : Wo;
    f16* dst = (mat < 3) ? (wt_qkv + (size_t)mat*DIM*DIM) : wo_t;
    int tx = tid & 31, ty = tid >> 5;    // (32, 8)
    #pragma unroll
    for (int i = 0; i < 32; i += 8)
      tile[ty+i][tx] = (f16)src[(size_t)(k0+ty+i)*DIM + n0+tx];
    __syncthreads();
    #pragma unroll
    for (int i = 0; i < 32; i += 8)
      dst[(size_t)(n0+ty+i)*DIM + k0+tx] = tile[tx][ty+i];
  } else {                               // ---- rope cos/sin tables ----
    int idx = (bid - 9216)*256 + tid;    // 0..131071
    int t = idx >> 5, d = idx & 31;
    float theta = exp2f(-(float)d * (19.931568569324174f / 32.0f));
    float sv, cv;
    sincosf((float)t * theta, &sv, &cv);
    ctab[idx] = cv; stab[idx] = sv;
  }
}

// ------------- m97-style 128x128 GEMM core: C = A[M,512] * Bt[N,512]^T -------------
__device__ __forceinline__ void gemm128_acc(
    const f16* __restrict__ A, const f16* __restrict__ Bt,
    int m0, int n0, f16* As, f16* Bs, f32x4 (&acc)[4][4]) {
  const int tid = threadIdx.x;
  const int wave = tid >> 6, lane = tid & 63;
  const int l16 = lane & 15, quad = lane >> 4;
  const int mrow = (wave & 1) * 64, ncol = (wave >> 1) * 64;
  const int srow = tid >> 3;                    // 0..31
  const int gc = (tid & 7) ^ ((tid >> 3) & 7);  // swizzled source chunk

  for (int k0 = 0; k0 < DIM; k0 += 64) {
    if (k0) __syncthreads();
    #pragma unroll
    for (int i = 0; i < 4; i++) {
      gld16(A  + (size_t)(m0 + i*32 + srow)*DIM + k0 + gc*8, As + i*2048 + tid*8);
      gld16(Bt + (size_t)(n0 + i*32 + srow)*DIM + k0 + gc*8, Bs + i*2048 + tid*8);
    }
    __syncthreads();
    #pragma unroll
    for (int kc = 0; kc < 2; kc++) {
      f16x8 a[4], b[4];
      #pragma unroll
      for (int mt = 0; mt < 4; mt++) {
        int row = mrow + mt*16 + l16;
        a[mt] = *(const f16x8*)(As + row*64 + (((quad + 4*kc) ^ (l16 & 7)) * 8));
      }
      #pragma unroll
      for (int nt = 0; nt < 4; nt++) {
        int row = ncol + nt*16 + l16;
        b[nt] = *(const f16x8*)(Bs + row*64 + (((quad + 4*kc) ^ (l16 & 7)) * 8));
      }
      #pragma unroll
      for (int mt = 0; mt < 4; mt++)
        #pragma unroll
        for (int nt = 0; nt < 4; nt++)
          acc[mt][nt] = __builtin_amdgcn_mfma_f32_16x16x32_f16(a[mt], b[nt], acc[mt][nt], 0, 0, 0);
    }
  }
}

// ------------- QKV GEMM + table-RoPE + Q prescale (r13 epilogue) -------------
// V output layout: within each 64-token group, token at permuted position
// pos = ((mt>>1)*4 + quad)*8 + (mt&1)*4 + r  so the attn PV fragment for
// (chunk c, quad) is ONE contiguous f16x8 matching the in-register P order
// sigma(c,quad,j) = (2c + (j>>2))*16 + quad*4 + (j&3).  [verified r9-r17]
__global__ __launch_bounds__(256) void qkv_gemm_kernel(
    const f16* __restrict__ xn, const f16* __restrict__ wt,
    const float* __restrict__ ctab, const float* __restrict__ stab,
    f16* __restrict__ qbuf, f16* __restrict__ kbuf, f16* __restrict__ vt) {
  __shared__ __align__(16) f16 As[128*64], Bs[128*64];
  int m0 = blockIdx.x * 128, n0 = blockIdx.y * 128;
  f32x4 acc[4][4] = {};
  gemm128_acc(xn, wt, m0, n0, As, Bs, acc);

  const int tid = threadIdx.x;
  const int wave = tid >> 6, lane = tid & 63;
  const int l16 = lane & 15, quad = lane >> 4;
  int ncol = n0 + (wave >> 1) * 64;      // head-aligned
  int which = ncol >> 9;                 // 0=q 1=k 2=v (wave-uniform)
  int head = (ncol >> 6) & 7;
  int mbase = m0 + (wave & 1) * 64;

  if (which <= 1) {                      // fused RoPE from tables
    #pragma unroll
    for (int mt = 0; mt < 4; mt++)
      #pragma unroll
      for (int nt = 0; nt < 2; nt++) {
        int d = nt*16 + l16;
        #pragma unroll
        for (int r = 0; r < 4; r++) {
          int t = (mbase + mt*16 + quad*4 + r) & 4095;
          float cv = ctab[t*32 + d], sv = stab[t*32 + d];
          float x1 = acc[mt][nt][r], x2 = acc[mt][nt+2][r];
          acc[mt][nt][r]   = x1*cv - x2*sv;
          acc[mt][nt+2][r] = x1*sv + x2*cv;
        }
      }
  }
  if (which < 2) {
    float osc = (which == 0) ? QSCALE : 1.0f;
    f16* dst = which ? kbuf : qbuf;
    #pragma unroll
    for (int mt = 0; mt < 4; mt++)
      #pragma unroll
      for (int nt = 0; nt < 4; nt++)
        #pragma unroll
        for (int r = 0; r < 4; r++) {
          int m = mbase + mt*16 + quad*4 + r;
          int b = m >> 12, t = m & 4095;
          dst[(((size_t)(b*NH + head))*S_LEN + t)*DH + nt*16 + l16] = (f16)(acc[mt][nt][r]*osc);
        }
  } else {                               // V transposed + pi-permuted token order
    #pragma unroll
    for (int mt = 0; mt < 4; mt++)
      #pragma unroll
      for (int nt = 0; nt < 4; nt++) {
        int m = mbase + mt*16 + quad*4;
        int b = m >> 12, tcol = m & 4095;
        int grp = tcol & ~63;
        int pos = ((mt >> 1)*4 + quad)*8 + (mt & 1)*4;
        int d = nt*16 + l16;
        f16x4 v4 = {(f16)acc[mt][nt][0], (f16)acc[mt][nt][1],
                    (f16)acc[mt][nt][2], (f16)acc[mt][nt][3]};
        *(f16x4*)(vt + ((size_t)((b*NH + head)*DH + d))*S_LEN + grp + pos) = v4;
      }
  }
}

// ------------- Flash attention (causal), band-specialized + split-K parity -------------
// r13 structure (best measured: 83.0us attn, 189.4us total). 2048 blocks x 256
// threads. Block = (pair p, parity hf, bh). Wave w owns ONE band (bi = w>>1) and
// one 16-row half (w&1). Tiles g = 2*itl + hf; partials to po/pm/pl; merge combines.
// r18 micro: row-max reassociated into a v_max3 tree (same result; shorter chain).
__global__ __launch_bounds__(256, 5) void attn_kernel(
    const f16* __restrict__ qbuf, const f16* __restrict__ kbuf,
    const f16* __restrict__ vtb, f16* __restrict__ po,
    float* __restrict__ pm, float* __restrict__ pl) {
  int bid = blockIdx.x;                  // 0..2047
  int bh  = bid & 15;
  int hf  = (bid >> 4) & 1;              // KV-tile parity half
  int p   = bid >> 5;                    // pair index 0..63

  int tid = threadIdx.x;
  int wave = tid >> 6, lane = tid & 63;
  int l16 = lane & 15, quad = lane >> 4;
  int bi = wave >> 1, half = wave & 1;

  const f16* Q = qbuf + (size_t)bh*S_LEN*DH;
  const f16* K = kbuf + (size_t)bh*S_LEN*DH;
  const f16* V = vtb  + (size_t)bh*DH*S_LEN;   // [dh][s], pi-permuted in s

  int bv = bi ? p : (127 - p);           // this wave's band (32 q-rows)
  int tc = (bv >> 1) + 1;                // its KV-tile count
  int T0 = ((127 - p) >> 1) + 1;         // heavy band tile count (block loop basis)
  int nloc = (T0 - hf + 1) >> 1;         // this parity's loop count
  int rbase = bv*32 + half*16;           // wave's 16 q-rows

  // Q fragments (B-operand of S^T = K Q^T)
  f16x8 qa0, qa1;
  {
    const f16* qrow = Q + (size_t)(rbase + l16)*DH + quad*8;
    qa0 = *(const f16x8*)(qrow);
    qa1 = *(const f16x8*)(qrow + 32);
  }

  f32x4 o[4] = {};                       // O C-layout [qrow=quad*4+r][dh=dnt*16+l16]
  float m_i = -1e30f;
  float l_i = 0.f;                       // per-lane partial (this quad); reduced in epilogue

  // K [2 bufs][64 kv][64 dh], V [2 bufs][64 dh][64 kv(perm)]  (32 KB)
  __shared__ __align__(16) f16 kt[2*4096];
  __shared__ __align__(16) f16 vs[2*4096];

  const int srow = tid >> 3;                     // 0..31
  const int gcs = (tid & 7) ^ (srow & 7);        // swizzled source chunk

  #define STAGE(buf, kv)                                                        \
    do {                                                                        \
      f16* ktb = kt + (buf)*4096;                                               \
      f16* vsb = vs + (buf)*4096;                                               \
      _Pragma("unroll")                                                         \
      for (int n = 0; n < 2; n++) {                                             \
        gld16(K + (size_t)((kv) + n*32 + srow)*DH + gcs*8, ktb + n*2048 + tid*8);\
        gld16(V + (size_t)(n*32 + srow)*S_LEN + (kv) + gcs*8, vsb + n*2048 + tid*8);\
      }                                                                         \
    } while (0)

  STAGE(0, hf*64);
  __syncthreads();                       // drains vmcnt -> first tile staged

  for (int itl = 0; itl < nloc; ++itl) {
    int g = 2*itl + hf;
    int kv0 = g * 64;
    int cur = itl & 1;
    if (itl + 1 < nloc) STAGE(cur ^ 1, kv0 + 128);   // async prefetch next parity tile

    const f16* ktc = kt + cur*4096;
    const f16* vsc = vs + cur*4096;

    if (g < tc) {                        // wave-uniform: this band still active
      bool diag = (g == tc - 1);
      int ntl = diag ? ((bv & 1) ? 4 : 2) : 4;    // live 16-key frags
      int kcl = ntl >> 1;                         // live 32-key chunks

      // ---- S^T = K Q^T ----
      f32x4 st[4];
      #pragma unroll
      for (int nt = 0; nt < 4; nt++) {
        if (nt >= ntl) continue;
        int row = nt*16 + l16;
        f16x8 kf0 = *(const f16x8*)(ktc + row*64 + (((quad)     ^ (row & 7))*8));
        f16x8 kf1 = *(const f16x8*)(ktc + row*64 + (((quad + 4) ^ (row & 7))*8));
        f32x4 z = {};
        z = __builtin_amdgcn_mfma_f32_16x16x32_f16(kf0, qa0, z, 0, 0, 0);
        st[nt] = __builtin_amdgcn_mfma_f32_16x16x32_f16(kf1, qa1, z, 0, 0, 0);
      }

      // ---- causal mask (diagonal tile only) ----
      int qglob = rbase + l16;
      if (diag) {
        #pragma unroll
        for (int nt = 0; nt < 4; nt++) {
          if (nt >= ntl) continue;
          int kb = kv0 + nt*16 + quad*4;
          #pragma unroll
          for (int r = 0; r < 4; r++)
            if (kb + r > qglob) st[nt][r] = -1e30f;
        }
      }
      // ---- row max: balanced v_max3 tree (exact reassociation) ----
      float rmx;
      if (ntl == 4) {
        float a0 = fmax3(st[0][0], st[0][1], st[0][2]);
        float a1 = fmax3(st[0][3], st[1][0], st[1][1]);
        float a2 = fmax3(st[1][2], st[1][3], st[2][0]);
        float a3 = fmax3(st[2][1], st[2][2], st[2][3]);
        float a4 = fmax3(st[3][0], st[3][1], st[3][2]);
        float b0 = fmax3(a0, a1, a2);
        float b1 = fmax3(a3, a4, st[3][3]);
        rmx = fmaxf(b0, b1);
      } else {
        float a0 = fmax3(st[0][0], st[0][1], st[0][2]);
        float a1 = fmax3(st[0][3], st[1][0], st[1][1]);
        rmx = fmax3(a0, a1, fmaxf(st[1][2], st[1][3]));
      }
      rmx = fmaxf(rmx, __shfl_xor(rmx, 16));
      rmx = fmaxf(rmx, __shfl_xor(rmx, 32));
      // defer-max (T13): skip O-rescale while running max grows < THR=8
      if (!__all(rmx <= m_i + 8.0f)) {
        float mnew = fmaxf(m_i, rmx);
        float alpha = fexp2(m_i - mnew);
        m_i = mnew;
        float al[4];
        #pragma unroll
        for (int r = 0; r < 4; r++) al[r] = __shfl(alpha, quad*4 + r);
        #pragma unroll
        for (int dnt = 0; dnt < 4; dnt++)
          #pragma unroll
          for (int r = 0; r < 4; r++) o[dnt][r] *= al[r];
        l_i *= alpha;
      }
      float mref = m_i;
      float rs = 0.f;
      f16x8 pa[2];
      #pragma unroll
      for (int c = 0; c < 2; c++) {
        if (c >= kcl) continue;
        float e0 = fexp2(st[2*c  ][0] - mref);
        float e1 = fexp2(st[2*c  ][1] - mref);
        float e2 = fexp2(st[2*c  ][2] - mref);
        float e3 = fexp2(st[2*c  ][3] - mref);
        float e4 = fexp2(st[2*c+1][0] - mref);
        float e5 = fexp2(st[2*c+1][1] - mref);
        float e6 = fexp2(st[2*c+1][2] - mref);
        float e7 = fexp2(st[2*c+1][3] - mref);
        rs += ((e0+e1)+(e2+e3)) + ((e4+e5)+(e6+e7));
        f16x4 h0 = __builtin_shufflevector(pk2(e0,e1), pk2(e2,e3), 0,1,2,3);
        f16x4 h1 = __builtin_shufflevector(pk2(e4,e5), pk2(e6,e7), 0,1,2,3);
        pa[c] = __builtin_shufflevector(h0, h1, 0,1,2,3,4,5,6,7);
      }
      l_i += rs;

      // ---- PV: one b128 V read per fragment (perm layout) ----
      #pragma unroll
      for (int c = 0; c < 2; c++) {
        if (c >= kcl) continue;
        #pragma unroll
        for (int dnt = 0; dnt < 4; dnt++) {
          int vr = dnt*16 + l16;
          f16x8 vf = *(const f16x8*)(vsc + vr*64 + (((c*4 + quad) ^ (vr & 7))*8));
          o[dnt] = __builtin_amdgcn_mfma_f32_16x16x32_f16(pa[c], vf, o[dnt], 0, 0, 0);
        }
      }
    }

    __syncthreads();  // all waves done reading cur; staged loads (vmcnt) drained
  }
  #undef STAGE

  // epilogue: write normalized partials + (m, l) per row
  {
    float lf = l_i;
    lf += __shfl_xor(lf, 16);
    lf += __shfl_xor(lf, 32);            // row-consistent l (indexed by l16)
    if (quad == 0) {                      // one lane per row writes m, l
      int t = rbase + l16;
      pm[(size_t)(hf*BHDIM + bh)*S_LEN + t] = m_i;
      pl[(size_t)(hf*BHDIM + bh)*S_LEN + t] = lf;
    }
    float lr[4];
    #pragma unroll
    for (int r = 0; r < 4; r++) lr[r] = __shfl(lf, quad*4 + r);
    #pragma unroll
    for (int r = 0; r < 4; r++) {
      float invl = (lr[r] > 0.f) ? 1.0f / lr[r] : 0.f;
      int t = rbase + quad*4 + r;
      size_t rowoff = ((size_t)(hf*BHDIM + bh)*S_LEN + t)*DH;
      #pragma unroll
      for (int dnt = 0; dnt < 4; dnt++)
        po[rowoff + dnt*16 + l16] = (f16)(o[dnt][r]*invl);
    }
  }
}

// ------------- Merge split-K halves: ao = w0*po0 + w1*po1 -------------
__global__ __launch_bounds__(256) void merge_kernel(
    const f16* __restrict__ po, const float* __restrict__ pm,
    const float* __restrict__ pl, f16* __restrict__ ao) {
  int idx = blockIdx.x*256 + threadIdx.x;     // 0..262143
  int r_ = idx >> 2, q = idx & 3;             // row, 16-dim quarter
  int bh = r_ >> 12, t = r_ & 4095;
  float m0 = pm[r_], m1 = pm[ROWS2 + r_];
  float l0 = pl[r_], l1 = pl[ROWS2 + r_];
  float M  = fmaxf(m0, m1);
  float a0 = l0 * fexp2(m0 - M);
  float a1 = l1 * fexp2(m1 - M);
  float inv = 1.0f / (a0 + a1);
  float w0 = a0 * inv, w1 = a1 * inv;
  const f16* p0 = po + (size_t)r_*DH + q*16;
  const f16* p1 = po + (size_t)(ROWS2 + r_)*DH + q*16;
  int b = bh >> 3, h = bh & 7;
  f16* dst = ao + ((size_t)(b*S_LEN + t))*DIM + h*DH + q*16;
  f16x8 v0a = *(const f16x8*)(p0), v0b = *(const f16x8*)(p0 + 8);
  f16x8 v1a = *(const f16x8*)(p1), v1b = *(const f16x8*)(p1 + 8);
  f16x8 oa, ob;
  #pragma unroll
  for (int j = 0; j < 8; j++) {
    oa[j] = (f16)(w0*(float)v0a[j] + w1*(float)v1a[j]);
    ob[j] = (f16)(w0*(float)v0b[j] + w1*(float)v1b[j]);
  }
  *(f16x8*)dst = oa;
  *(f16x8*)(dst + 8) = ob;
}

// ------------- Output GEMM: ao[8192,512] @ Wo -> out f32 -------------
__global__ __launch_bounds__(256) void out_gemm_kernel(
    const f16* __restrict__ ao, const f16* __restrict__ wot,
    float* __restrict__ out) {
  __shared__ __align__(16) f16 As[128*64], Bs[128*64];
  int m0 = blockIdx.x * 128, n0 = blockIdx.y * 128;
  f32x4 acc[4][4] = {};
  gemm128_acc(ao, wot, m0, n0, As, Bs, acc);

  const int tid = threadIdx.x;
  const int wave = tid >> 6, lane = tid & 63;
  const int l16 = lane & 15, quad = lane >> 4;
  int ncol = n0 + (wave >> 1) * 64;
  int mbase = m0 + (wave & 1) * 64;
  #pragma unroll
  for (int mt = 0; mt < 4; mt++)
    #pragma unroll
    for (int nt = 0; nt < 4; nt++)
      #pragma unroll
      for (int r = 0; r < 4; r++)
        out[(size_t)(mbase + mt*16 + quad*4 + r)*DIM + ncol + nt*16 + l16] = acc[mt][nt][r];
}

extern "C" void kernel_launch(void* const* d_in, const int* in_sizes, int n_in,
                              void* d_out, int out_size, void* d_ws, size_t ws_size,
                              hipStream_t stream) {
  const float* x     = (const float*)d_in[0];
  const float* scale = (const float*)d_in[1];
  const float* Wq    = (const float*)d_in[2];
  const float* Wk    = (const float*)d_in[3];
  const float* Wv    = (const float*)d_in[4];
  const float* Wo    = (const float*)d_in[5];
  float* out = (float*)d_out;

  const size_t ROWS = (size_t)BATCH * S_LEN;   // 8192
  char* ws = (char*)d_ws;
  f16* xn     = (f16*)ws;  ws += ROWS * DIM * sizeof(f16);            // 8 MB (reused as ao)
  f16* wt_qkv = (f16*)ws;  ws += (size_t)3 * DIM * DIM * sizeof(f16); // 1.5 MB
  f16* wo_t   = (f16*)ws;  ws += (size_t)DIM * DIM * sizeof(f16);     // 0.5 MB
  f16* qb     = (f16*)ws;  ws += (size_t)BHDIM * S_LEN * DH * sizeof(f16); // 8 MB
  f16* kb     = (f16*)ws;  ws += (size_t)BHDIM * S_LEN * DH * sizeof(f16); // 8 MB
  f16* vt     = (f16*)ws;  ws += (size_t)BHDIM * S_LEN * DH * sizeof(f16); // 8 MB
  float* ctab = (float*)ws; ws += (size_t)S_LEN * 32 * sizeof(float);  // 0.5 MB
  float* stab = (float*)ws; ws += (size_t)S_LEN * 32 * sizeof(float);  // 0.5 MB
  f16* po     = (f16*)ws;  ws += (size_t)2 * ROWS2 * DH * sizeof(f16); // 16.8 MB
  float* pm   = (float*)ws; ws += (size_t)2 * ROWS2 * sizeof(float);   // 0.5 MB
  float* pl   = (float*)ws; ws += (size_t)2 * ROWS2 * sizeof(float);   // 0.5 MB
  f16* ao     = xn;  // overlay: xn dead after qkv_gemm

  size_t need = (size_t)(ws - (char*)d_ws);
  if (ws_size < need) return;

  prep_kernel    <<<9728, 256, 0, stream>>>(x, scale, Wq, Wk, Wv, Wo,
                                            xn, wt_qkv, wo_t, ctab, stab);
  qkv_gemm_kernel<<<dim3(64,12), 256, 0, stream>>>(xn, wt_qkv, ctab, stab, qb, kb, vt);
  attn_kernel    <<<2048, 256, 0, stream>>>(qb, kb, vt, po, pm, pl);
  merge_kernel   <<<1024, 256, 0, stream>>>(po, pm, pl, ao);
  out_gemm_kernel<<<dim3(64,4), 256, 0, stream>>>(ao, wo_t, out);
}